// Round 6
// baseline (244.028 us; speedup 1.0000x reference)
//
#include <hip/hip_runtime.h>

typedef unsigned short u16;
typedef unsigned int u32;
typedef __attribute__((ext_vector_type(8))) __bf16 bf16x8;
typedef __attribute__((ext_vector_type(4))) float f32x4;
typedef __attribute__((ext_vector_type(4))) unsigned int u32x4;

#define MFMA16(a, b, c) __builtin_amdgcn_mfma_f32_16x16x32_bf16((a), (b), (c), 0, 0, 0)

__device__ __forceinline__ u16 f2bf(float f) {
  unsigned u = __float_as_uint(f);
  u += 0x7FFFu + ((u >> 16) & 1u);
  return (u16)(u >> 16);
}

typedef __attribute__((address_space(1))) const unsigned char gU8;
typedef __attribute__((address_space(3))) unsigned char sU8;
__device__ __forceinline__ void gload16(const void* g, void* l) {
  __builtin_amdgcn_global_load_lds((gU8*)g, (sU8*)l, 16, 0, 0);
}

// ================= fused pre-pass: batched-MLP weight transposes + wperm + LN1 =================
__device__ __forceinline__ void wt_body(const float* __restrict__ W, u16* __restrict__ Wt,
                                        int K, int N, int bid, float* tile) {
  int ntn = N >> 6;
  int kt = bid / ntn, nt = bid % ntn;
  int t = threadIdx.x;
  const float* src = W + (size_t)kt * 64 * N + (size_t)nt * 64;
  // phase 1: all 4 global loads in flight before any LDS write
  f32x4 r[4];
#pragma unroll
  for (int i = 0; i < 4; ++i) {
    int idx = t + i * 256, row = idx >> 4, c4 = idx & 15;
    r[i] = *(const f32x4*)&src[(size_t)row * N + c4 * 4];
  }
#pragma unroll
  for (int i = 0; i < 4; ++i) {
    int idx = t + i * 256, row = idx >> 4, c4 = idx & 15;
#pragma unroll
    for (int j = 0; j < 4; ++j) tile[row * 65 + c4 * 4 + j] = r[i][j];
  }
  __syncthreads();
  // phase 2: all 16 LDS column reads in flight before packing
  int nn0 = t >> 3, k8 = t & 7;
  float v[2][8];
#pragma unroll
  for (int i = 0; i < 2; ++i)
#pragma unroll
    for (int j = 0; j < 8; ++j) v[i][j] = tile[(k8 * 8 + j) * 65 + nn0 + i * 32];
  u16* dst = Wt + (size_t)nt * 64 * K + (size_t)kt * 64;
#pragma unroll
  for (int i = 0; i < 2; ++i) {
    u32x4 pk;
#pragma unroll
    for (int j = 0; j < 4; ++j)
      pk[j] = (u32)f2bf(v[i][2 * j]) | ((u32)f2bf(v[i][2 * j + 1]) << 16);
    *(u32x4*)&dst[(size_t)(nn0 + i * 32) * K + k8 * 8] = pk;
  }
}

__device__ __forceinline__ void wperm_body(const float* __restrict__ Wrk, const float* __restrict__ Wrv,
                                           u16* __restrict__ Wtk, u16* __restrict__ Wtv, int bid) {
  int idx = bid * 256 + threadIdx.x;  // 16384 = 64 c' * 256 f
  int cp = idx >> 8, f = idx & 255;
  int k = ((f & 63) << 2) | (f >> 6);
  Wtk[idx] = f2bf(Wrk[k * 64 + cp]);
  Wtv[idx] = f2bf(Wrv[k * 64 + cp]);
}

__device__ __forceinline__ void ln1_body(const float* __restrict__ x, const float* __restrict__ w,
                                         const float* __restrict__ bias, u16* __restrict__ xf_pc,
                                         u16* __restrict__ xfT, int bid, float* tile) {
  int b = bid >> 6, p0 = (bid & 63) << 6;
  int t = threadIdx.x;
  const float* xb = x + (size_t)b * 64 * 4096;
  f32x4 r[4];
#pragma unroll
  for (int i = 0; i < 4; ++i) {
    int idx = t + i * 256, c = idx >> 4, p4 = idx & 15;
    r[i] = *(const f32x4*)&xb[(size_t)c * 4096 + p0 + p4 * 4];
  }
#pragma unroll
  for (int i = 0; i < 4; ++i) {
    int idx = t + i * 256, c = idx >> 4, p4 = idx & 15;
#pragma unroll
    for (int j = 0; j < 4; ++j) tile[c * 65 + p4 * 4 + j] = r[i][j];
  }
  __syncthreads();
  int lane = t & 63, wvx = t >> 6;
  float gw = w[lane], gb = bias[lane];
  // per-pixel LN over channels, 2 pixels interleaved for shuffle ILP
#pragma unroll
  for (int pp = 0; pp < 16; pp += 2) {
    int p = wvx * 16 + pp;
    float v0 = tile[lane * 65 + p], v1 = tile[lane * 65 + p + 1];
    float s0 = v0, q0 = v0 * v0, s1 = v1, q1 = v1 * v1;
#pragma unroll
    for (int m = 1; m < 64; m <<= 1) {
      s0 += __shfl_xor(s0, m); q0 += __shfl_xor(q0, m);
      s1 += __shfl_xor(s1, m); q1 += __shfl_xor(q1, m);
    }
    float mu0 = s0 * (1.0f / 64.0f), var0 = q0 * (1.0f / 64.0f) - mu0 * mu0;
    float mu1 = s1 * (1.0f / 64.0f), var1 = q1 * (1.0f / 64.0f) - mu1 * mu1;
    tile[lane * 65 + p]     = (v0 - mu0) * rsqrtf(var0 + 1e-5f) * gw + gb;
    tile[lane * 65 + p + 1] = (v1 - mu1) * rsqrtf(var1 + 1e-5f) * gw + gb;
  }
  __syncthreads();
  u16* xfb = xf_pc + (size_t)b * 4096 * 64;
  u16* xtb = xfT + (size_t)b * 64 * 4096;
  int i0 = t >> 3, j8 = t & 7;
  // xf_pc[p][c]: 16 column reads batched
  float vc[2][8];
#pragma unroll
  for (int i = 0; i < 2; ++i)
#pragma unroll
    for (int j = 0; j < 8; ++j) vc[i][j] = tile[(j8 * 8 + j) * 65 + i0 + i * 32];
#pragma unroll
  for (int i = 0; i < 2; ++i) {
    u32x4 pk;
#pragma unroll
    for (int j = 0; j < 4; ++j)
      pk[j] = (u32)f2bf(vc[i][2 * j]) | ((u32)f2bf(vc[i][2 * j + 1]) << 16);
    *(u32x4*)&xfb[(size_t)(p0 + i0 + i * 32) * 64 + j8 * 8] = pk;
  }
  // xfT[c][p]: 16 row reads batched
  float vr[2][8];
#pragma unroll
  for (int i = 0; i < 2; ++i)
#pragma unroll
    for (int j = 0; j < 8; ++j) vr[i][j] = tile[(i0 + i * 32) * 65 + j8 * 8 + j];
#pragma unroll
  for (int i = 0; i < 2; ++i) {
    u32x4 pk;
#pragma unroll
    for (int j = 0; j < 4; ++j)
      pk[j] = (u32)f2bf(vr[i][2 * j]) | ((u32)f2bf(vr[i][2 * j + 1]) << 16);
    *(u32x4*)&xtb[(size_t)(i0 + i * 32) * 4096 + p0 + j8 * 8] = pk;
  }
}

__global__ __launch_bounds__(256) void prep_kernel(
    const float* __restrict__ W_q, u16* __restrict__ Wt_q,
    const float* __restrict__ W_o, u16* __restrict__ Wt_o,
    const float* __restrict__ W_k, u16* __restrict__ Wt_k,
    const float* __restrict__ W_v, u16* __restrict__ Wt_v,
    const float* __restrict__ W_rk, const float* __restrict__ W_rv,
    u16* __restrict__ Wt_rk, u16* __restrict__ Wt_rv,
    const float* __restrict__ x, const float* __restrict__ ln1w, const float* __restrict__ ln1b,
    u16* __restrict__ xf_pc, u16* __restrict__ xfT) {
  __shared__ float tile[64 * 65];
  int bid = blockIdx.x;
  if (bid < 4096)       wt_body(W_q, Wt_q, 4096, 4096, bid, tile);
  else if (bid < 8192)  wt_body(W_o, Wt_o, 4096, 4096, bid - 4096, tile);
  else if (bid < 8448)  wt_body(W_k, Wt_k, 1024, 1024, bid - 8192, tile);
  else if (bid < 8704)  wt_body(W_v, Wt_v, 1024, 1024, bid - 8448, tile);
  else if (bid < 8768)  wperm_body(W_rk, W_rv, Wt_rk, Wt_rv, bid - 8704);
  else                  ln1_body(x, ln1w, ln1b, xf_pc, xfT, bid - 8768, tile);
}

// ================= KV spatial reduction GEMM (64x64x256) + LN2 + transposed store =================
__global__ __launch_bounds__(256) void kv_kernel(const u16* __restrict__ xf_pc,
                                                 const u16* __restrict__ Wtk, const u16* __restrict__ Wtv,
                                                 const float* __restrict__ ln2w, const float* __restrict__ ln2b,
                                                 u16* __restrict__ kT, u16* __restrict__ vT) {
  __shared__ __align__(16) u16 As[64 * 264];
  __shared__ __align__(16) u16 Bk[64 * 264];
  __shared__ __align__(16) u16 Bv[64 * 264];
  u16* Tk = As;            // reuse As after compute (needs 64*72)
  u16* Tv = As + 64 * 72;  // 2*64*72 = 9216 <= 64*264
  int b = blockIdx.x >> 4, s0 = (blockIdx.x & 15) << 6;
  int t = threadIdx.x;
  const u16* Asrc = xf_pc + (size_t)b * 4096 * 64 + (size_t)s0 * 256;
#pragma unroll
  for (int i = 0; i < 8; ++i) {
    int id = t + i * 256, row = id >> 5, c16 = id & 31;
    *(u32x4*)&As[row * 264 + c16 * 8] = *(const u32x4*)&Asrc[(size_t)row * 256 + c16 * 8];
    *(u32x4*)&Bk[row * 264 + c16 * 8] = *(const u32x4*)&Wtk[(size_t)row * 256 + c16 * 8];
    *(u32x4*)&Bv[row * 264 + c16 * 8] = *(const u32x4*)&Wtv[(size_t)row * 256 + c16 * 8];
  }
  __syncthreads();
  int lane = t & 63, wv = t >> 6, lo = lane & 15, hi = lane >> 4;
  f32x4 acck[4] = {}, accv[4] = {};
  int arow = (wv * 16 + lo) * 264 + hi * 8;
#pragma unroll
  for (int kk = 0; kk < 8; ++kk) {
    bf16x8 a = *(const bf16x8*)&As[arow + kk * 32];
#pragma unroll
    for (int nf = 0; nf < 4; ++nf) {
      bf16x8 bk = *(const bf16x8*)&Bk[(nf * 16 + lo) * 264 + kk * 32 + hi * 8];
      bf16x8 bv = *(const bf16x8*)&Bv[(nf * 16 + lo) * 264 + kk * 32 + hi * 8];
      acck[nf] = MFMA16(a, bk, acck[nf]);
      accv[nf] = MFMA16(a, bv, accv[nf]);
    }
  }
  __syncthreads();  // done reading As; Tk/Tv alias it
  float w2[4], b2[4];
#pragma unroll
  for (int nf = 0; nf < 4; ++nf) { w2[nf] = ln2w[nf * 16 + lo]; b2[nf] = ln2b[nf * 16 + lo]; }
#pragma unroll
  for (int r = 0; r < 4; ++r) {
    float sk = 0.f, sk2 = 0.f, sv = 0.f, sv2 = 0.f;
#pragma unroll
    for (int nf = 0; nf < 4; ++nf) {
      float a = acck[nf][r], c = accv[nf][r];
      sk += a; sk2 += a * a; sv += c; sv2 += c * c;
    }
#pragma unroll
    for (int m = 1; m < 16; m <<= 1) {
      sk += __shfl_xor(sk, m); sk2 += __shfl_xor(sk2, m);
      sv += __shfl_xor(sv, m); sv2 += __shfl_xor(sv2, m);
    }
    float mk = sk * (1.f / 64.f), vk = sk2 * (1.f / 64.f) - mk * mk, rk = rsqrtf(vk + 1e-5f);
    float mv = sv * (1.f / 64.f), vv = sv2 * (1.f / 64.f) - mv * mv, rv = rsqrtf(vv + 1e-5f);
    int srow = wv * 16 + hi * 4 + r;
#pragma unroll
    for (int nf = 0; nf < 4; ++nf) {
      Tk[(nf * 16 + lo) * 72 + srow] = f2bf((acck[nf][r] - mk) * rk * w2[nf] + b2[nf]);
      Tv[(nf * 16 + lo) * 72 + srow] = f2bf((accv[nf][r] - mv) * rv * w2[nf] + b2[nf]);
    }
  }
  __syncthreads();
  u16* kdst = kT + (size_t)b * 64 * 1024 + s0;
  u16* vdst = vT + (size_t)b * 64 * 1024 + s0;
#pragma unroll
  for (int i = 0; i < 16; ++i) {
    int idx = t + i * 256, cp = idx >> 6, s = idx & 63;
    kdst[(size_t)cp * 1024 + s] = Tk[cp * 72 + s];
    vdst[(size_t)cp * 1024 + s] = Tv[cp * 72 + s];
  }
}

// ================= GEMM body: 3-buffer counted-vmcnt pipeline + XOR-swizzled LDS =================
// LDS layout per buffer: As[128][8 slots of 16B], slot s of row r holds global chunk s^(r&7).
// Achieved by pre-swizzling the per-lane GLOBAL source (linear gload_lds dest, rule m173).
__device__ __forceinline__ void stage_tile(const u16* Ab, const u16* Bb, int K, int kt,
                                           u16* As, u16* Bs, int wv, int lane) {
  int r8 = lane >> 3;                       // row within 8-row chunk
  int gcol = ((lane & 7) ^ r8) << 3;        // swizzled 16B-chunk within 64-col row
  const u16* a0 = Ab + (size_t)kt * 64 + gcol;
  const u16* b0 = Bb + (size_t)kt * 64 + gcol;
#pragma unroll
  for (int i = 0; i < 4; ++i) {
    int chunk = wv * 4 + i;
    int row = chunk * 8 + r8;
    gload16(a0 + (size_t)row * K, As + chunk * 512);
    gload16(b0 + (size_t)row * K, Bs + chunk * 512);
  }
}

__device__ __forceinline__ void compute_tile(const u16* As, const u16* Bs, f32x4 acc[4][4],
                                             int wm, int wn, int lo, int hi) {
  int sa = lo & 7;
#pragma unroll
  for (int kk = 0; kk < 2; ++kk) {
    int slot = ((kk * 4 + hi) ^ sa) << 3;
    bf16x8 a[4], bb[4];
#pragma unroll
    for (int i = 0; i < 4; ++i) {
      a[i]  = *(const bf16x8*)&As[(wm + i * 16 + lo) * 64 + slot];
      bb[i] = *(const bf16x8*)&Bs[(wn + i * 16 + lo) * 64 + slot];
    }
#pragma unroll
    for (int mi = 0; mi < 4; ++mi)
#pragma unroll
      for (int ni = 0; ni < 4; ++ni)
        acc[mi][ni] = MFMA16(a[mi], bb[ni], acc[mi][ni]);
  }
}

// EPI 0: bf16 store C[m*N+n]
// EPI 1: bf16 store C[(n>>6)*chunkStride + m*64 + (n&63)]   (batch-split columns)
template <int EPI>
__device__ void gemm_body(const u16* __restrict__ A, const u16* __restrict__ Bm,
                          u16* __restrict__ Cc, int N, int K, int chunkStride,
                          int mt, int nt, int koff, int nk, u16* lds) {
  int t = threadIdx.x, lane = t & 63, wv = t >> 6;
  int wm = (wv >> 1) * 64, wn = (wv & 1) * 64;
  int lo = lane & 15, hi = lane >> 4;
  f32x4 acc[4][4] = {};
  const u16* Ab = A + (size_t)mt * 128 * K + koff;
  const u16* Bb = Bm + (size_t)nt * 128 * K + koff;
  // 3 buffers x (A 16KB + B 16KB) = 96KB
  u16* buf[3] = {lds, lds + 16384, lds + 32768};
  stage_tile(Ab, Bb, K, 0, buf[0], buf[0] + 8192, wv, lane);
  stage_tile(Ab, Bb, K, 1, buf[1], buf[1] + 8192, wv, lane);
  for (int kt = 0; kt < nk; ++kt) {
    // counted wait: stage kt retired, stage kt+1 (8 loads) may stay in flight
    if (kt + 1 < nk) asm volatile("s_waitcnt vmcnt(8)" ::: "memory");
    else             asm volatile("s_waitcnt vmcnt(0)" ::: "memory");
    __builtin_amdgcn_s_barrier();
    __builtin_amdgcn_sched_barrier(0);
    int nxt = kt + 2;
    if (nxt < nk) {
      u16* nb = buf[nxt % 3];  // freed: computed in iter kt-1, all waves past barrier
      stage_tile(Ab, Bb, K, nxt, nb, nb + 8192, wv, lane);
    }
    u16* cb = buf[kt % 3];
    compute_tile(cb, cb + 8192, acc, wm, wn, lo, hi);
  }
#pragma unroll
  for (int mi = 0; mi < 4; ++mi)
#pragma unroll
    for (int ni = 0; ni < 4; ++ni)
#pragma unroll
      for (int r = 0; r < 4; ++r) {
        int m = mt * 128 + wm + mi * 16 + hi * 4 + r;
        int n = nt * 128 + wn + ni * 16 + lo;
        float v = acc[mi][ni][r];
        if constexpr (EPI == 0) {
          Cc[(size_t)m * N + n] = f2bf(v);
        } else {
          Cc[(size_t)(n >> 6) * chunkStride + (size_t)m * 64 + (n & 63)] = f2bf(v);
        }
      }
}

// fused Q(split-K=4, 1024 blocks) + K(64) + V(64) projections
__global__ __launch_bounds__(256, 1) void qkv_kernel(
    const u16* __restrict__ Wt_q, const u16* __restrict__ xfT, u16* __restrict__ q_t,
    const u16* __restrict__ Wt_k, const u16* __restrict__ k_lnT, u16* __restrict__ kproj,
    const u16* __restrict__ v_lnT, const u16* __restrict__ Wt_v, u16* __restrict__ vproj) {
  __shared__ __align__(16) u16 lds[49152];
  int bid = blockIdx.x;
  if (bid < 1024) {
    // bijective XCD swizzle (nwg=1024): blocks sharing an A-panel land on one XCD
    int log = (bid & 7) * 128 + (bid >> 3);
    int kh = log >> 8, tile = log & 255, mt = tile >> 3, nt = tile & 7;
    gemm_body<1>(Wt_q, xfT, q_t + (size_t)kh * 4194304, 1024, 4096, 4096 * 64,
                 mt, nt, kh * 1024, 16, lds);
  } else if (bid < 1088) {
    int id = bid - 1024;
    gemm_body<1>(Wt_k, k_lnT, kproj, 1024, 1024, 1024 * 64, id >> 3, id & 7, 0, 16, lds);
  } else {
    int id = bid - 1088;
    gemm_body<0>(v_lnT, Wt_v, vproj, 1024, 1024, 0, id >> 3, id & 7, 0, 16, lds);
  }
}

// O-projection, split-K=2, 512 blocks, bf16 partials
__global__ __launch_bounds__(256, 1) void ogemm_kernel(const u16* __restrict__ o2,
                                                       const u16* __restrict__ Wt_o,
                                                       u16* __restrict__ o_part) {
  __shared__ __align__(16) u16 lds[49152];
  int bid = blockIdx.x;
  int log = (bid & 7) * 64 + (bid >> 3);
  int kh = log >> 8, tile = log & 255, mt = tile >> 5, nt = tile & 31;
  gemm_body<0>(o2, Wt_o, o_part + (size_t)kh * 4194304, 4096, 4096, 0,
               mt, nt, kh * 2048, 32, lds);
}

// out = x + p0 + p1   (f32 residual fused into split-K reduce)
__global__ __launch_bounds__(256) void oreduce_kernel(const float* __restrict__ x,
                                                      const u16* __restrict__ p0,
                                                      const u16* __restrict__ p1,
                                                      float* __restrict__ out) {
  size_t base = ((size_t)blockIdx.x * 256 + threadIdx.x) * 8;
  u32x4 a = *(const u32x4*)&p0[base];
  u32x4 b = *(const u32x4*)&p1[base];
  f32x4 x0 = *(const f32x4*)&x[base];
  f32x4 x1 = *(const f32x4*)&x[base + 4];
  float r[8];
#pragma unroll
  for (int j = 0; j < 4; ++j) {
    r[2 * j]     = __uint_as_float(a[j] << 16) + __uint_as_float(b[j] << 16);
    r[2 * j + 1] = __uint_as_float(a[j] & 0xFFFF0000u) + __uint_as_float(b[j] & 0xFFFF0000u);
  }
  f32x4 o0, o1;
#pragma unroll
  for (int j = 0; j < 4; ++j) { o0[j] = r[j] + x0[j]; o1[j] = r[4 + j] + x1[j]; }
  *(f32x4*)&out[base] = o0;
  *(f32x4*)&out[base + 4] = o1;
}

// ================= attention: per (b, head, 128-row q tile); full K (128) per block =================
__global__ __launch_bounds__(256) void attn_kernel(const u16* __restrict__ qp, const u16* __restrict__ kp,
                                                   const u16* __restrict__ vp, u16* __restrict__ o2) {
  __shared__ __align__(16) u16 Qs[128 * 72];
  __shared__ __align__(16) u16 Ks[128 * 72];
  __shared__ __align__(16) u16 Vs[64 * 136];
  __shared__ __align__(16) u16 Ps[128 * 136];
  int qt = blockIdx.x & 3, h = (blockIdx.x >> 2) & 7, b = blockIdx.x >> 5;
  int t = threadIdx.x, lane = t & 63, wv = t >> 6;
  int lo = lane & 15, hi = lane >> 4;
  const u16* qsrc = qp + (size_t)b * 262144 + (size_t)(h * 512 + qt * 128) * 64;
  const u16* ksrc = kp + (size_t)b * 1024 * 64 + (size_t)(h * 128) * 64;
  const u16* vsrc = vp + (size_t)b * 64 * 1024 + h * 128;
  // Q: sum 4 split-K bf16 partials, repack to bf16 (128 rows x 64 cols = 4 iters)
#pragma unroll
  for (int i = 0; i < 4; ++i) {
    int id = t + i * 256, row = id >> 3, c8 = id & 7;
    size_t goff = (size_t)row * 64 + c8 * 8;
    float f[8] = {0.f, 0.f, 0.f, 0.f, 0.f, 0.f, 0.f, 0.f};
#pragma unroll
    for (int kh = 0; kh < 4; ++kh) {
      u32x4 pk = *(const u32x4*)&qsrc[(size_t)kh * 4194304 + goff];
#pragma unroll
      for (int j = 0; j < 4; ++j) {
        f[2 * j]     += __uint_as_float(pk[j] << 16);
        f[2 * j + 1] += __uint_as_float(pk[j] & 0xFFFF0000u);
      }
    }
    u32x4 pko;
#pragma unroll
    for (int j = 0; j < 4; ++j) pko[j] = (u32)f2bf(f[2 * j]) | ((u32)f2bf(f[2 * j + 1]) << 16);
    *(u32x4*)&Qs[row * 72 + c8 * 8] = pko;
  }
#pragma unroll
  for (int i = 0; i < 4; ++i) {
    int id = t + i * 256;
    int row = id >> 3, c16 = id & 7;
    *(u32x4*)&Ks[row * 72 + c16 * 8] = *(const u32x4*)&ksrc[(size_t)row * 64 + c16 * 8];
    int vrow = id >> 4, v16 = id & 15;
    *(u32x4*)&Vs[vrow * 136 + v16 * 8] = *(const u32x4*)&vsrc[(size_t)vrow * 1024 + v16 * 8];
  }
  __syncthreads();
  // S = Q K^T : each wave owns 32 q-rows x 128 k-cols
  f32x4 s[2][8] = {};
#pragma unroll
  for (int kk = 0; kk < 2; ++kk) {
    bf16x8 a0 = *(const bf16x8*)&Qs[(wv * 32 + lo) * 72 + kk * 32 + hi * 8];
    bf16x8 a1 = *(const bf16x8*)&Qs[(wv * 32 + 16 + lo) * 72 + kk * 32 + hi * 8];
#pragma unroll
    for (int ni = 0; ni < 8; ++ni) {
      bf16x8 bb = *(const bf16x8*)&Ks[(ni * 16 + lo) * 72 + kk * 32 + hi * 8];
      s[0][ni] = MFMA16(a0, bb, s[0][ni]);
      s[1][ni] = MFMA16(a1, bb, s[1][ni]);
    }
  }
  const float inv_scale = 0.044194173824159216f;  // 1/sqrt(512)
#pragma unroll
  for (int mi = 0; mi < 2; ++mi)
#pragma unroll
    for (int ni = 0; ni < 8; ++ni) s[mi][ni] *= inv_scale;
#pragma unroll
  for (int mi = 0; mi < 2; ++mi) {
#pragma unroll
    for (int r = 0; r < 4; ++r) {
      float mx = -1e30f;
#pragma unroll
      for (int ni = 0; ni < 8; ++ni) mx = fmaxf(mx, s[mi][ni][r]);
#pragma unroll
      for (int m = 1; m < 16; m <<= 1) mx = fmaxf(mx, __shfl_xor(mx, m));
      float p[8], sum = 0.f;
#pragma unroll
      for (int ni = 0; ni < 8; ++ni) { p[ni] = __expf(s[mi][ni][r] - mx); sum += p[ni]; }
#pragma unroll
      for (int m = 1; m < 16; m <<= 1) sum += __shfl_xor(sum, m);
      float rs = 1.0f / sum;
      int row = wv * 32 + mi * 16 + hi * 4 + r;
#pragma unroll
      for (int ni = 0; ni < 8; ++ni) Ps[row * 136 + ni * 16 + lo] = f2bf(p[ni] * rs);
    }
  }
  __syncthreads();
  // O^T[c][lq] = sum_lk V[c][lk] * P[lq][lk] : each wave owns 64 c-rows x 32 lq-cols
  f32x4 o[4][2] = {};
#pragma unroll
  for (int kk = 0; kk < 4; ++kk) {
    bf16x8 b0 = *(const bf16x8*)&Ps[(wv * 32 + lo) * 136 + kk * 32 + hi * 8];
    bf16x8 b1 = *(const bf16x8*)&Ps[(wv * 32 + 16 + lo) * 136 + kk * 32 + hi * 8];
#pragma unroll
    for (int mi = 0; mi < 4; ++mi) {
      bf16x8 a = *(const bf16x8*)&Vs[(mi * 16 + lo) * 136 + kk * 32 + hi * 8];
      o[mi][0] = MFMA16(a, b0, o[mi][0]);
      o[mi][1] = MFMA16(a, b1, o[mi][1]);
    }
  }
  u16* od = o2 + (size_t)b * 64 * 4096 + h * 512 + qt * 128;
#pragma unroll
  for (int mi = 0; mi < 4; ++mi)
#pragma unroll
    for (int ni = 0; ni < 2; ++ni)
#pragma unroll
      for (int r = 0; r < 4; ++r) {
        int c = mi * 16 + hi * 4 + r;
        int lq = wv * 32 + ni * 16 + lo;
        od[(size_t)c * 4096 + lq] = f2bf(o[mi][ni][r]);
      }
}

extern "C" void kernel_launch(void* const* d_in, const int* in_sizes, int n_in,
                              void* d_out, int out_size, void* d_ws, size_t ws_size,
                              hipStream_t stream) {
  (void)in_sizes; (void)n_in; (void)out_size; (void)ws_size;
  const float* x    = (const float*)d_in[0];
  const float* ln1w = (const float*)d_in[1];
  const float* ln1b = (const float*)d_in[2];
  const float* ln2w = (const float*)d_in[3];
  const float* ln2b = (const float*)d_in[4];
  const float* W_rk = (const float*)d_in[5];
  const float* W_rv = (const float*)d_in[6];
  const float* W_q  = (const float*)d_in[7];
  const float* W_k  = (const float*)d_in[8];
  const float* W_v  = (const float*)d_in[9];
  const float* W_o  = (const float*)d_in[10];

  char* ws = (char*)d_ws;
  size_t off = 0;
  auto alloc = [&](size_t bytes) { char* p = ws + off; off += bytes; return p; };
  u16* Wt_q  = (u16*)alloc(4096ull * 4096 * 2);   // dead after qkv -> reused as o_part
  u16* Wt_o  = (u16*)alloc(4096ull * 4096 * 2);
  u16* Wt_k  = (u16*)alloc(1024ull * 1024 * 2);
  u16* Wt_v  = (u16*)alloc(1024ull * 1024 * 2);
  u16* Wt_rk = (u16*)alloc(64ull * 256 * 2);
  u16* Wt_rv = (u16*)alloc(64ull * 256 * 2);
  u16* xf_pc = (u16*)alloc(16ull * 4096 * 64 * 2);
  u16* xfT   = (u16*)alloc(16ull * 64 * 4096 * 2);  // dead after qkv -> reused as o2
  u16* k_lnT = (u16*)alloc(16ull * 64 * 1024 * 2);
  u16* v_lnT = (u16*)alloc(16ull * 64 * 1024 * 2);
  u16* q_t   = (u16*)alloc(4ull * 16 * 4096 * 64 * 2);  // 4 split-K partials
  u16* kproj = (u16*)alloc(16ull * 1024 * 64 * 2);
  u16* vproj = (u16*)alloc(16ull * 64 * 1024 * 2);
  u16* o2     = xfT;   // alias: xfT dead after qkv, o2 written by attn
  u16* o_part = Wt_q;  // alias: Wt_q dead after qkv, 2 partials (16.8 MB <= 33.5 MB)

  prep_kernel<<<9792, 256, 0, stream>>>(W_q, Wt_q, W_o, Wt_o, W_k, Wt_k, W_v, Wt_v,
                                        W_rk, W_rv, Wt_rk, Wt_rv, x, ln1w, ln1b, xf_pc, xfT);
  kv_kernel<<<256, 256, 0, stream>>>(xf_pc, Wt_rk, Wt_rv, ln2w, ln2b, k_lnT, v_lnT);
  // Q: q_t[kh][b][j][c] partials;  K: kproj[b][jk][c];  V: vproj[(b,c)][jv]
  qkv_kernel<<<1152, 256, 0, stream>>>(Wt_q, xfT, q_t, Wt_k, k_lnT, kproj, v_lnT, Wt_v, vproj);
  attn_kernel<<<512, 256, 0, stream>>>(q_t, kproj, vproj, o2);
  // O: o_part[kh][(b,c)][j2] = sum_j o2[(b,c)][j] * Wt_o[j2][j]
  ogemm_kernel<<<512, 256, 0, stream>>>(o2, Wt_o, o_part);
  oreduce_kernel<<<2048, 256, 0, stream>>>(x, o_part, o_part + 4194304, (float*)d_out);
}

// Round 7
// 212.852 us; speedup vs baseline: 1.1465x; 1.1465x over previous
//
#include <hip/hip_runtime.h>

typedef unsigned short u16;
typedef unsigned int u32;
typedef __attribute__((ext_vector_type(8))) __bf16 bf16x8;
typedef __attribute__((ext_vector_type(4))) float f32x4;
typedef __attribute__((ext_vector_type(4))) unsigned int u32x4;

#define MFMA16(a, b, c) __builtin_amdgcn_mfma_f32_16x16x32_bf16((a), (b), (c), 0, 0, 0)

__device__ __forceinline__ u16 f2bf(float f) {
  unsigned u = __float_as_uint(f);
  u += 0x7FFFu + ((u >> 16) & 1u);
  return (u16)(u >> 16);
}

typedef __attribute__((address_space(1))) const unsigned char gU8;
typedef __attribute__((address_space(3))) unsigned char sU8;
__device__ __forceinline__ void gload16(const void* g, void* l) {
  __builtin_amdgcn_global_load_lds((gU8*)g, (sU8*)l, 16, 0, 0);
}

// ================= fused pre-pass: batched-MLP weight transposes + wperm + LN1 =================
__device__ __forceinline__ void wt_body(const float* __restrict__ W, u16* __restrict__ Wt,
                                        int K, int N, int bid, float* tile) {
  int ntn = N >> 6;
  int kt = bid / ntn, nt = bid % ntn;
  int t = threadIdx.x;
  const float* src = W + (size_t)kt * 64 * N + (size_t)nt * 64;
  f32x4 r[4];
#pragma unroll
  for (int i = 0; i < 4; ++i) {
    int idx = t + i * 256, row = idx >> 4, c4 = idx & 15;
    r[i] = *(const f32x4*)&src[(size_t)row * N + c4 * 4];
  }
#pragma unroll
  for (int i = 0; i < 4; ++i) {
    int idx = t + i * 256, row = idx >> 4, c4 = idx & 15;
#pragma unroll
    for (int j = 0; j < 4; ++j) tile[row * 65 + c4 * 4 + j] = r[i][j];
  }
  __syncthreads();
  int nn0 = t >> 3, k8 = t & 7;
  float v[2][8];
#pragma unroll
  for (int i = 0; i < 2; ++i)
#pragma unroll
    for (int j = 0; j < 8; ++j) v[i][j] = tile[(k8 * 8 + j) * 65 + nn0 + i * 32];
  u16* dst = Wt + (size_t)nt * 64 * K + (size_t)kt * 64;
#pragma unroll
  for (int i = 0; i < 2; ++i) {
    u32x4 pk;
#pragma unroll
    for (int j = 0; j < 4; ++j)
      pk[j] = (u32)f2bf(v[i][2 * j]) | ((u32)f2bf(v[i][2 * j + 1]) << 16);
    *(u32x4*)&dst[(size_t)(nn0 + i * 32) * K + k8 * 8] = pk;
  }
}

__device__ __forceinline__ void wperm_body(const float* __restrict__ Wrk, const float* __restrict__ Wrv,
                                           u16* __restrict__ Wtk, u16* __restrict__ Wtv, int bid) {
  int idx = bid * 256 + threadIdx.x;  // 16384 = 64 c' * 256 f
  int cp = idx >> 8, f = idx & 255;
  int k = ((f & 63) << 2) | (f >> 6);
  Wtk[idx] = f2bf(Wrk[k * 64 + cp]);
  Wtv[idx] = f2bf(Wrv[k * 64 + cp]);
}

__device__ __forceinline__ void ln1_body(const float* __restrict__ x, const float* __restrict__ w,
                                         const float* __restrict__ bias, u16* __restrict__ xf_pc,
                                         u16* __restrict__ xfT, int bid, float* tile) {
  int b = bid >> 6, p0 = (bid & 63) << 6;
  int t = threadIdx.x;
  const float* xb = x + (size_t)b * 64 * 4096;
  f32x4 r[4];
#pragma unroll
  for (int i = 0; i < 4; ++i) {
    int idx = t + i * 256, c = idx >> 4, p4 = idx & 15;
    r[i] = *(const f32x4*)&xb[(size_t)c * 4096 + p0 + p4 * 4];
  }
#pragma unroll
  for (int i = 0; i < 4; ++i) {
    int idx = t + i * 256, c = idx >> 4, p4 = idx & 15;
#pragma unroll
    for (int j = 0; j < 4; ++j) tile[c * 65 + p4 * 4 + j] = r[i][j];
  }
  __syncthreads();
  int lane = t & 63, wvx = t >> 6;
  float gw = w[lane], gb = bias[lane];
#pragma unroll
  for (int pp = 0; pp < 16; pp += 2) {
    int p = wvx * 16 + pp;
    float v0 = tile[lane * 65 + p], v1 = tile[lane * 65 + p + 1];
    float s0 = v0, q0 = v0 * v0, s1 = v1, q1 = v1 * v1;
#pragma unroll
    for (int m = 1; m < 64; m <<= 1) {
      s0 += __shfl_xor(s0, m); q0 += __shfl_xor(q0, m);
      s1 += __shfl_xor(s1, m); q1 += __shfl_xor(q1, m);
    }
    float mu0 = s0 * (1.0f / 64.0f), var0 = q0 * (1.0f / 64.0f) - mu0 * mu0;
    float mu1 = s1 * (1.0f / 64.0f), var1 = q1 * (1.0f / 64.0f) - mu1 * mu1;
    tile[lane * 65 + p]     = (v0 - mu0) * rsqrtf(var0 + 1e-5f) * gw + gb;
    tile[lane * 65 + p + 1] = (v1 - mu1) * rsqrtf(var1 + 1e-5f) * gw + gb;
  }
  __syncthreads();
  u16* xfb = xf_pc + (size_t)b * 4096 * 64;
  u16* xtb = xfT + (size_t)b * 64 * 4096;
  int i0 = t >> 3, j8 = t & 7;
  float vc[2][8];
#pragma unroll
  for (int i = 0; i < 2; ++i)
#pragma unroll
    for (int j = 0; j < 8; ++j) vc[i][j] = tile[(j8 * 8 + j) * 65 + i0 + i * 32];
#pragma unroll
  for (int i = 0; i < 2; ++i) {
    u32x4 pk;
#pragma unroll
    for (int j = 0; j < 4; ++j)
      pk[j] = (u32)f2bf(vc[i][2 * j]) | ((u32)f2bf(vc[i][2 * j + 1]) << 16);
    *(u32x4*)&xfb[(size_t)(p0 + i0 + i * 32) * 64 + j8 * 8] = pk;
  }
  float vr[2][8];
#pragma unroll
  for (int i = 0; i < 2; ++i)
#pragma unroll
    for (int j = 0; j < 8; ++j) vr[i][j] = tile[(i0 + i * 32) * 65 + j8 * 8 + j];
#pragma unroll
  for (int i = 0; i < 2; ++i) {
    u32x4 pk;
#pragma unroll
    for (int j = 0; j < 4; ++j)
      pk[j] = (u32)f2bf(vr[i][2 * j]) | ((u32)f2bf(vr[i][2 * j + 1]) << 16);
    *(u32x4*)&xtb[(size_t)(i0 + i * 32) * 4096 + p0 + j8 * 8] = pk;
  }
}

__global__ __launch_bounds__(256) void prep_kernel(
    const float* __restrict__ W_q, u16* __restrict__ Wt_q,
    const float* __restrict__ W_o, u16* __restrict__ Wt_o,
    const float* __restrict__ W_k, u16* __restrict__ Wt_k,
    const float* __restrict__ W_v, u16* __restrict__ Wt_v,
    const float* __restrict__ W_rk, const float* __restrict__ W_rv,
    u16* __restrict__ Wt_rk, u16* __restrict__ Wt_rv,
    const float* __restrict__ x, const float* __restrict__ ln1w, const float* __restrict__ ln1b,
    u16* __restrict__ xf_pc, u16* __restrict__ xfT) {
  __shared__ float tile[64 * 65];
  int bid = blockIdx.x;
  if (bid < 4096)       wt_body(W_q, Wt_q, 4096, 4096, bid, tile);
  else if (bid < 8192)  wt_body(W_o, Wt_o, 4096, 4096, bid - 4096, tile);
  else if (bid < 8448)  wt_body(W_k, Wt_k, 1024, 1024, bid - 8192, tile);
  else if (bid < 8704)  wt_body(W_v, Wt_v, 1024, 1024, bid - 8448, tile);
  else if (bid < 8768)  wperm_body(W_rk, W_rv, Wt_rk, Wt_rv, bid - 8704);
  else                  ln1_body(x, ln1w, ln1b, xf_pc, xfT, bid - 8768, tile);
}

// ================= KV spatial reduction GEMM (64x64x256) + LN2 + transposed store =================
__global__ __launch_bounds__(256) void kv_kernel(const u16* __restrict__ xf_pc,
                                                 const u16* __restrict__ Wtk, const u16* __restrict__ Wtv,
                                                 const float* __restrict__ ln2w, const float* __restrict__ ln2b,
                                                 u16* __restrict__ kT, u16* __restrict__ vT) {
  __shared__ __align__(16) u16 As[64 * 264];
  __shared__ __align__(16) u16 Bk[64 * 264];
  __shared__ __align__(16) u16 Bv[64 * 264];
  u16* Tk = As;            // reuse As after compute (needs 64*72)
  u16* Tv = As + 64 * 72;  // 2*64*72 = 9216 <= 64*264
  int b = blockIdx.x >> 4, s0 = (blockIdx.x & 15) << 6;
  int t = threadIdx.x;
  const u16* Asrc = xf_pc + (size_t)b * 4096 * 64 + (size_t)s0 * 256;
#pragma unroll
  for (int i = 0; i < 8; ++i) {
    int id = t + i * 256, row = id >> 5, c16 = id & 31;
    *(u32x4*)&As[row * 264 + c16 * 8] = *(const u32x4*)&Asrc[(size_t)row * 256 + c16 * 8];
    *(u32x4*)&Bk[row * 264 + c16 * 8] = *(const u32x4*)&Wtk[(size_t)row * 256 + c16 * 8];
    *(u32x4*)&Bv[row * 264 + c16 * 8] = *(const u32x4*)&Wtv[(size_t)row * 256 + c16 * 8];
  }
  __syncthreads();
  int lane = t & 63, wv = t >> 6, lo = lane & 15, hi = lane >> 4;
  f32x4 acck[4] = {}, accv[4] = {};
  int arow = (wv * 16 + lo) * 264 + hi * 8;
#pragma unroll
  for (int kk = 0; kk < 8; ++kk) {
    bf16x8 a = *(const bf16x8*)&As[arow + kk * 32];
#pragma unroll
    for (int nf = 0; nf < 4; ++nf) {
      bf16x8 bk = *(const bf16x8*)&Bk[(nf * 16 + lo) * 264 + kk * 32 + hi * 8];
      bf16x8 bv = *(const bf16x8*)&Bv[(nf * 16 + lo) * 264 + kk * 32 + hi * 8];
      acck[nf] = MFMA16(a, bk, acck[nf]);
      accv[nf] = MFMA16(a, bv, accv[nf]);
    }
  }
  __syncthreads();  // done reading As; Tk/Tv alias it
  float w2[4], b2[4];
#pragma unroll
  for (int nf = 0; nf < 4; ++nf) { w2[nf] = ln2w[nf * 16 + lo]; b2[nf] = ln2b[nf * 16 + lo]; }
#pragma unroll
  for (int r = 0; r < 4; ++r) {
    float sk = 0.f, sk2 = 0.f, sv = 0.f, sv2 = 0.f;
#pragma unroll
    for (int nf = 0; nf < 4; ++nf) {
      float a = acck[nf][r], c = accv[nf][r];
      sk += a; sk2 += a * a; sv += c; sv2 += c * c;
    }
#pragma unroll
    for (int m = 1; m < 16; m <<= 1) {
      sk += __shfl_xor(sk, m); sk2 += __shfl_xor(sk2, m);
      sv += __shfl_xor(sv, m); sv2 += __shfl_xor(sv2, m);
    }
    float mk = sk * (1.f / 64.f), vk = sk2 * (1.f / 64.f) - mk * mk, rk = rsqrtf(vk + 1e-5f);
    float mv = sv * (1.f / 64.f), vv = sv2 * (1.f / 64.f) - mv * mv, rv = rsqrtf(vv + 1e-5f);
    int srow = wv * 16 + hi * 4 + r;
#pragma unroll
    for (int nf = 0; nf < 4; ++nf) {
      Tk[(nf * 16 + lo) * 72 + srow] = f2bf((acck[nf][r] - mk) * rk * w2[nf] + b2[nf]);
      Tv[(nf * 16 + lo) * 72 + srow] = f2bf((accv[nf][r] - mv) * rv * w2[nf] + b2[nf]);
    }
  }
  __syncthreads();
  u16* kdst = kT + (size_t)b * 64 * 1024 + s0;
  u16* vdst = vT + (size_t)b * 64 * 1024 + s0;
#pragma unroll
  for (int i = 0; i < 16; ++i) {
    int idx = t + i * 256, cp = idx >> 6, s = idx & 63;
    kdst[(size_t)cp * 1024 + s] = Tk[cp * 72 + s];
    vdst[(size_t)cp * 1024 + s] = Tv[cp * 72 + s];
  }
}

// ================= GEMM: BK=32, 3-buffer (48KB) counted-vmcnt pipeline, 4-slot XOR swizzle ==========
// Buffer: A[128][32] + B[128][32] bf16 = 16KB. Row r, 16B-slot s holds source k-chunk s^(r&3)
// (pre-swizzled global source, linear gload_lds dest — rule m173/21).
__device__ __forceinline__ void stage32(const u16* Ab, const u16* Bb, int K, int kt,
                                        u16* As, u16* Bs, int wv, int lane) {
#pragma unroll
  for (int i = 0; i < 2; ++i) {
    int cb = wv * 2 + i;            // uniform 1KB chunk-block
    int c = cb * 64 + lane;         // this lane's 16B chunk index
    int row = c >> 2, s = c & 3;
    int scol = (s ^ (row & 3)) << 3;
    gload16(Ab + (size_t)row * K + kt * 32 + scol, As + cb * 512);
    gload16(Bb + (size_t)row * K + kt * 32 + scol, Bs + cb * 512);
  }
}

__device__ __forceinline__ void compute32(const u16* As, const u16* Bs, f32x4 acc[4][4],
                                          int wm, int wn, int lo, int hi) {
  int slot = (hi ^ (lo & 3)) << 3;  // physical slot of logical k-chunk hi for rows ≡ lo (mod 4)
  bf16x8 a[4], bb[4];
#pragma unroll
  for (int i = 0; i < 4; ++i) {
    a[i]  = *(const bf16x8*)&As[(wm + i * 16 + lo) * 32 + slot];
    bb[i] = *(const bf16x8*)&Bs[(wn + i * 16 + lo) * 32 + slot];
  }
#pragma unroll
  for (int mi = 0; mi < 4; ++mi)
#pragma unroll
    for (int ni = 0; ni < 4; ++ni)
      acc[mi][ni] = MFMA16(a[mi], bb[ni], acc[mi][ni]);
}

// EPI 0: bf16 store C[m*N+n]
// EPI 1: bf16 store C[(n>>6)*chunkStride + m*64 + (n&63)]   (batch-split columns)
template <int EPI>
__device__ void gemm_body(const u16* __restrict__ A, const u16* __restrict__ Bm,
                          u16* __restrict__ Cc, int N, int K, int chunkStride,
                          int mt, int nt, int koff, int nk, u16* lds) {
  int t = threadIdx.x, lane = t & 63, wv = t >> 6;
  int wm = (wv >> 1) * 64, wn = (wv & 1) * 64;
  int lo = lane & 15, hi = lane >> 4;
  f32x4 acc[4][4] = {};
  const u16* Ab = A + (size_t)mt * 128 * K + koff;
  const u16* Bb = Bm + (size_t)nt * 128 * K + koff;
  u16* bufs[3] = {lds, lds + 8192, lds + 16384};  // 3 x 16KB = 48KB -> 3 blocks/CU
  stage32(Ab, Bb, K, 0, bufs[0], bufs[0] + 4096, wv, lane);
  stage32(Ab, Bb, K, 1, bufs[1], bufs[1] + 4096, wv, lane);
  for (int kt = 0; kt < nk; ++kt) {
    // counted wait BEFORE barrier: my stage-kt loads (4) retired, stage-kt+1's may fly
    if (kt + 1 < nk) asm volatile("s_waitcnt vmcnt(4)" ::: "memory");
    else             asm volatile("s_waitcnt vmcnt(0)" ::: "memory");
    __builtin_amdgcn_s_barrier();
    __builtin_amdgcn_sched_barrier(0);
    if (kt + 2 < nk) {
      u16* nb = bufs[(kt + 2) % 3];  // last read in compute(kt-1); all waves past barrier
      stage32(Ab, Bb, K, kt + 2, nb, nb + 4096, wv, lane);
    }
    u16* cb = bufs[kt % 3];
    compute32(cb, cb + 4096, acc, wm, wn, lo, hi);
  }
#pragma unroll
  for (int mi = 0; mi < 4; ++mi)
#pragma unroll
    for (int ni = 0; ni < 4; ++ni)
#pragma unroll
      for (int r = 0; r < 4; ++r) {
        int m = mt * 128 + wm + mi * 16 + hi * 4 + r;
        int n = nt * 128 + wn + ni * 16 + lo;
        float v = acc[mi][ni][r];
        if constexpr (EPI == 0) {
          Cc[(size_t)m * N + n] = f2bf(v);
        } else {
          Cc[(size_t)(n >> 6) * chunkStride + (size_t)m * 64 + (n & 63)] = f2bf(v);
        }
      }
}

// fused Q(split-K=4, 1024 blocks) + K(64) + V(64) projections
__global__ __launch_bounds__(256, 3) void qkv_kernel(
    const u16* __restrict__ Wt_q, const u16* __restrict__ xfT, u16* __restrict__ q_t,
    const u16* __restrict__ Wt_k, const u16* __restrict__ k_lnT, u16* __restrict__ kproj,
    const u16* __restrict__ v_lnT, const u16* __restrict__ Wt_v, u16* __restrict__ vproj) {
  __shared__ __align__(16) u16 lds[24576];
  int bid = blockIdx.x;
  if (bid < 1024) {
    // bijective XCD swizzle (nwg=1024): blocks sharing an A-panel land on one XCD
    int log = (bid & 7) * 128 + (bid >> 3);
    int kh = log >> 8, tile = log & 255, mt = tile >> 3, nt = tile & 7;
    gemm_body<1>(Wt_q, xfT, q_t + (size_t)kh * 4194304, 1024, 4096, 4096 * 64,
                 mt, nt, kh * 1024, 32, lds);
  } else if (bid < 1088) {
    int id = bid - 1024;
    gemm_body<1>(Wt_k, k_lnT, kproj, 1024, 1024, 1024 * 64, id >> 3, id & 7, 0, 32, lds);
  } else {
    int id = bid - 1088;
    gemm_body<0>(v_lnT, Wt_v, vproj, 1024, 1024, 0, id >> 3, id & 7, 0, 32, lds);
  }
}

// O-projection, split-K=2, 512 blocks, bf16 partials
__global__ __launch_bounds__(256, 3) void ogemm_kernel(const u16* __restrict__ o2,
                                                       const u16* __restrict__ Wt_o,
                                                       u16* __restrict__ o_part) {
  __shared__ __align__(16) u16 lds[24576];
  int bid = blockIdx.x;
  int log = (bid & 7) * 64 + (bid >> 3);
  int kh = log >> 8, tile = log & 255, mt = tile >> 5, nt = tile & 31;
  gemm_body<0>(o2, Wt_o, o_part + (size_t)kh * 4194304, 4096, 4096, 0,
               mt, nt, kh * 2048, 64, lds);
}

// out = x + p0 + p1   (f32 residual fused into split-K reduce)
__global__ __launch_bounds__(256) void oreduce_kernel(const float* __restrict__ x,
                                                      const u16* __restrict__ p0,
                                                      const u16* __restrict__ p1,
                                                      float* __restrict__ out) {
  size_t base = ((size_t)blockIdx.x * 256 + threadIdx.x) * 8;
  u32x4 a = *(const u32x4*)&p0[base];
  u32x4 b = *(const u32x4*)&p1[base];
  f32x4 x0 = *(const f32x4*)&x[base];
  f32x4 x1 = *(const f32x4*)&x[base + 4];
  float r[8];
#pragma unroll
  for (int j = 0; j < 4; ++j) {
    r[2 * j]     = __uint_as_float(a[j] << 16) + __uint_as_float(b[j] << 16);
    r[2 * j + 1] = __uint_as_float(a[j] & 0xFFFF0000u) + __uint_as_float(b[j] & 0xFFFF0000u);
  }
  f32x4 o0, o1;
#pragma unroll
  for (int j = 0; j < 4; ++j) { o0[j] = r[j] + x0[j]; o1[j] = r[4 + j] + x1[j]; }
  *(f32x4*)&out[base] = o0;
  *(f32x4*)&out[base + 4] = o1;
}

// ================= attention: per (b, head, 128-row q tile); full K (128) per block =================
__global__ __launch_bounds__(256) void attn_kernel(const u16* __restrict__ qp, const u16* __restrict__ kp,
                                                   const u16* __restrict__ vp, u16* __restrict__ o2) {
  __shared__ __align__(16) u16 Qs[128 * 72];
  __shared__ __align__(16) u16 Ks[128 * 72];
  __shared__ __align__(16) u16 Vs[64 * 136];
  __shared__ __align__(16) u16 Ps[128 * 136];
  int qt = blockIdx.x & 3, h = (blockIdx.x >> 2) & 7, b = blockIdx.x >> 5;
  int t = threadIdx.x, lane = t & 63, wv = t >> 6;
  int lo = lane & 15, hi = lane >> 4;
  const u16* qsrc = qp + (size_t)b * 262144 + (size_t)(h * 512 + qt * 128) * 64;
  const u16* ksrc = kp + (size_t)b * 1024 * 64 + (size_t)(h * 128) * 64;
  const u16* vsrc = vp + (size_t)b * 64 * 1024 + h * 128;
  // Q: sum 4 split-K bf16 partials, repack to bf16 (128 rows x 64 cols = 4 iters)
#pragma unroll
  for (int i = 0; i < 4; ++i) {
    int id = t + i * 256, row = id >> 3, c8 = id & 7;
    size_t goff = (size_t)row * 64 + c8 * 8;
    float f[8] = {0.f, 0.f, 0.f, 0.f, 0.f, 0.f, 0.f, 0.f};
#pragma unroll
    for (int kh = 0; kh < 4; ++kh) {
      u32x4 pk = *(const u32x4*)&qsrc[(size_t)kh * 4194304 + goff];
#pragma unroll
      for (int j = 0; j < 4; ++j) {
        f[2 * j]     += __uint_as_float(pk[j] << 16);
        f[2 * j + 1] += __uint_as_float(pk[j] & 0xFFFF0000u);
      }
    }
    u32x4 pko;
#pragma unroll
    for (int j = 0; j < 4; ++j) pko[j] = (u32)f2bf(f[2 * j]) | ((u32)f2bf(f[2 * j + 1]) << 16);
    *(u32x4*)&Qs[row * 72 + c8 * 8] = pko;
  }
#pragma unroll
  for (int i = 0; i < 4; ++i) {
    int id = t + i * 256;
    int row = id >> 3, c16 = id & 7;
    *(u32x4*)&Ks[row * 72 + c16 * 8] = *(const u32x4*)&ksrc[(size_t)row * 64 + c16 * 8];
    int vrow = id >> 4, v16 = id & 15;
    *(u32x4*)&Vs[vrow * 136 + v16 * 8] = *(const u32x4*)&vsrc[(size_t)vrow * 1024 + v16 * 8];
  }
  __syncthreads();
  // S = Q K^T : each wave owns 32 q-rows x 128 k-cols
  f32x4 s[2][8] = {};
#pragma unroll
  for (int kk = 0; kk < 2; ++kk) {
    bf16x8 a0 = *(const bf16x8*)&Qs[(wv * 32 + lo) * 72 + kk * 32 + hi * 8];
    bf16x8 a1 = *(const bf16x8*)&Qs[(wv * 32 + 16 + lo) * 72 + kk * 32 + hi * 8];
#pragma unroll
    for (int ni = 0; ni < 8; ++ni) {
      bf16x8 bb = *(const bf16x8*)&Ks[(ni * 16 + lo) * 72 + kk * 32 + hi * 8];
      s[0][ni] = MFMA16(a0, bb, s[0][ni]);
      s[1][ni] = MFMA16(a1, bb, s[1][ni]);
    }
  }
  const float inv_scale = 0.044194173824159216f;  // 1/sqrt(512)
#pragma unroll
  for (int mi = 0; mi < 2; ++mi)
#pragma unroll
    for (int ni = 0; ni < 8; ++ni) s[mi][ni] *= inv_scale;
#pragma unroll
  for (int mi = 0; mi < 2; ++mi) {
#pragma unroll
    for (int r = 0; r < 4; ++r) {
      float mx = -1e30f;
#pragma unroll
      for (int ni = 0; ni < 8; ++ni) mx = fmaxf(mx, s[mi][ni][r]);
#pragma unroll
      for (int m = 1; m < 16; m <<= 1) mx = fmaxf(mx, __shfl_xor(mx, m));
      float p[8], sum = 0.f;
#pragma unroll
      for (int ni = 0; ni < 8; ++ni) { p[ni] = __expf(s[mi][ni][r] - mx); sum += p[ni]; }
#pragma unroll
      for (int m = 1; m < 16; m <<= 1) sum += __shfl_xor(sum, m);
      float rs = 1.0f / sum;
      int row = wv * 32 + mi * 16 + hi * 4 + r;
#pragma unroll
      for (int ni = 0; ni < 8; ++ni) Ps[row * 136 + ni * 16 + lo] = f2bf(p[ni] * rs);
    }
  }
  __syncthreads();
  // O^T[c][lq] = sum_lk V[c][lk] * P[lq][lk] : each wave owns 64 c-rows x 32 lq-cols
  f32x4 o[4][2] = {};
#pragma unroll
  for (int kk = 0; kk < 4; ++kk) {
    bf16x8 b0 = *(const bf16x8*)&Ps[(wv * 32 + lo) * 136 + kk * 32 + hi * 8];
    bf16x8 b1 = *(const bf16x8*)&Ps[(wv * 32 + 16 + lo) * 136 + kk * 32 + hi * 8];
#pragma unroll
    for (int mi = 0; mi < 4; ++mi) {
      bf16x8 a = *(const bf16x8*)&Vs[(mi * 16 + lo) * 136 + kk * 32 + hi * 8];
      o[mi][0] = MFMA16(a, b0, o[mi][0]);
      o[mi][1] = MFMA16(a, b1, o[mi][1]);
    }
  }
  u16* od = o2 + (size_t)b * 64 * 4096 + h * 512 + qt * 128;
#pragma unroll
  for (int mi = 0; mi < 4; ++mi)
#pragma unroll
    for (int ni = 0; ni < 2; ++ni)
#pragma unroll
      for (int r = 0; r < 4; ++r) {
        int c = mi * 16 + hi * 4 + r;
        int lq = wv * 32 + ni * 16 + lo;
        od[(size_t)c * 4096 + lq] = f2bf(o[mi][ni][r]);
      }
}

extern "C" void kernel_launch(void* const* d_in, const int* in_sizes, int n_in,
                              void* d_out, int out_size, void* d_ws, size_t ws_size,
                              hipStream_t stream) {
  (void)in_sizes; (void)n_in; (void)out_size; (void)ws_size;
  const float* x    = (const float*)d_in[0];
  const float* ln1w = (const float*)d_in[1];
  const float* ln1b = (const float*)d_in[2];
  const float* ln2w = (const float*)d_in[3];
  const float* ln2b = (const float*)d_in[4];
  const float* W_rk = (const float*)d_in[5];
  const float* W_rv = (const float*)d_in[6];
  const float* W_q  = (const float*)d_in[7];
  const float* W_k  = (const float*)d_in[8];
  const float* W_v  = (const float*)d_in[9];
  const float* W_o  = (const float*)d_in[10];

  char* ws = (char*)d_ws;
  size_t off = 0;
  auto alloc = [&](size_t bytes) { char* p = ws + off; off += bytes; return p; };
  u16* Wt_q  = (u16*)alloc(4096ull * 4096 * 2);   // dead after qkv -> reused as o_part
  u16* Wt_o  = (u16*)alloc(4096ull * 4096 * 2);
  u16* Wt_k  = (u16*)alloc(1024ull * 1024 * 2);
  u16* Wt_v  = (u16*)alloc(1024ull * 1024 * 2);
  u16* Wt_rk = (u16*)alloc(64ull * 256 * 2);
  u16* Wt_rv = (u16*)alloc(64ull * 256 * 2);
  u16* xf_pc = (u16*)alloc(16ull * 4096 * 64 * 2);
  u16* xfT   = (u16*)alloc(16ull * 64 * 4096 * 2);  // dead after qkv -> reused as o2
  u16* k_lnT = (u16*)alloc(16ull * 64 * 1024 * 2);
  u16* v_lnT = (u16*)alloc(16ull * 64 * 1024 * 2);
  u16* q_t   = (u16*)alloc(4ull * 16 * 4096 * 64 * 2);  // 4 split-K partials
  u16* kproj = (u16*)alloc(16ull * 1024 * 64 * 2);
  u16* vproj = (u16*)alloc(16ull * 64 * 1024 * 2);
  u16* o2     = xfT;   // alias: xfT dead after qkv, o2 written by attn
  u16* o_part = Wt_q;  // alias: Wt_q dead after qkv, 2 partials (16.8 MB <= 33.5 MB)

  prep_kernel<<<9792, 256, 0, stream>>>(W_q, Wt_q, W_o, Wt_o, W_k, Wt_k, W_v, Wt_v,
                                        W_rk, W_rv, Wt_rk, Wt_rv, x, ln1w, ln1b, xf_pc, xfT);
  kv_kernel<<<256, 256, 0, stream>>>(xf_pc, Wt_rk, Wt_rv, ln2w, ln2b, k_lnT, v_lnT);
  // Q: q_t[kh][b][j][c] partials;  K: kproj[b][jk][c];  V: vproj[(b,c)][jv]
  qkv_kernel<<<1152, 256, 0, stream>>>(Wt_q, xfT, q_t, Wt_k, k_lnT, kproj, v_lnT, Wt_v, vproj);
  attn_kernel<<<512, 256, 0, stream>>>(q_t, kproj, vproj, o2);
  // O: o_part[kh][(b,c)][j2] = sum_j o2[(b,c)][j] * Wt_o[j2][j]
  ogemm_kernel<<<512, 256, 0, stream>>>(o2, Wt_o, o_part);
  oreduce_kernel<<<2048, 256, 0, stream>>>(x, o_part, o_part + 4194304, (float*)d_out);
}

// Round 8
// 211.558 us; speedup vs baseline: 1.1535x; 1.0061x over previous
//
#include <hip/hip_runtime.h>

typedef unsigned short u16;
typedef unsigned int u32;
typedef __attribute__((ext_vector_type(8))) __bf16 bf16x8;
typedef __attribute__((ext_vector_type(4))) float f32x4;
typedef __attribute__((ext_vector_type(4))) unsigned int u32x4;

#define MFMA16(a, b, c) __builtin_amdgcn_mfma_f32_16x16x32_bf16((a), (b), (c), 0, 0, 0)

__device__ __forceinline__ u16 f2bf(float f) {
  unsigned u = __float_as_uint(f);
  u += 0x7FFFu + ((u >> 16) & 1u);
  return (u16)(u >> 16);
}

typedef __attribute__((address_space(1))) const unsigned char gU8;
typedef __attribute__((address_space(3))) unsigned char sU8;
__device__ __forceinline__ void gload16(const void* g, void* l) {
  __builtin_amdgcn_global_load_lds((gU8*)g, (sU8*)l, 16, 0, 0);
}

// ================= fused pre-pass: 2-deep weight transposes + wperm + LN1 =================
// wt_body2: one block transposes a 128k x 64n strip of W (f32, [K][N]) into Wt[n][k] bf16.
// All 8 global f32x4 loads issued before any LDS write; ONE barrier per strip.
__device__ __forceinline__ void wt_body2(const float* __restrict__ W, u16* __restrict__ Wt,
                                         int K, int N, int bid, float* tile) {
  int ntn = N >> 6;
  int kt2 = bid / ntn, nt = bid % ntn;
  int t = threadIdx.x;
  const float* src = W + (size_t)kt2 * 128 * N + (size_t)nt * 64;
  f32x4 r[8];
#pragma unroll
  for (int i = 0; i < 8; ++i) {
    int idx = t + i * 256, row = idx >> 4, c4 = idx & 15;
    r[i] = *(const f32x4*)&src[(size_t)row * N + c4 * 4];
  }
#pragma unroll
  for (int i = 0; i < 8; ++i) {
    int idx = t + i * 256, row = idx >> 4, c4 = idx & 15;
#pragma unroll
    for (int j = 0; j < 4; ++j) tile[row * 65 + c4 * 4 + j] = r[i][j];
  }
  __syncthreads();
  // output: 64 n-rows x 128 k; thread (g = t&7) covers k = g*16..g*16+15 of row n
  u16* dst = Wt + (size_t)nt * 64 * K + (size_t)kt2 * 128;
  int g = t & 7, n0 = t >> 3;
#pragma unroll
  for (int i = 0; i < 2; ++i) {
    int n = n0 + i * 32;
    float v[16];
#pragma unroll
    for (int j = 0; j < 16; ++j) v[j] = tile[(g * 16 + j) * 65 + n];
    u32x4 pk0, pk1;
#pragma unroll
    for (int j = 0; j < 4; ++j) {
      pk0[j] = (u32)f2bf(v[2 * j]) | ((u32)f2bf(v[2 * j + 1]) << 16);
      pk1[j] = (u32)f2bf(v[8 + 2 * j]) | ((u32)f2bf(v[8 + 2 * j + 1]) << 16);
    }
    *(u32x4*)&dst[(size_t)n * K + g * 16] = pk0;
    *(u32x4*)&dst[(size_t)n * K + g * 16 + 8] = pk1;
  }
}

__device__ __forceinline__ void wperm_body(const float* __restrict__ Wrk, const float* __restrict__ Wrv,
                                           u16* __restrict__ Wtk, u16* __restrict__ Wtv, int bid) {
  int idx = bid * 256 + threadIdx.x;  // 16384 = 64 c' * 256 f
  int cp = idx >> 8, f = idx & 255;
  int k = ((f & 63) << 2) | (f >> 6);
  Wtk[idx] = f2bf(Wrk[k * 64 + cp]);
  Wtv[idx] = f2bf(Wrv[k * 64 + cp]);
}

__device__ __forceinline__ void ln1_body(const float* __restrict__ x, const float* __restrict__ w,
                                         const float* __restrict__ bias, u16* __restrict__ xf_pc,
                                         u16* __restrict__ xfT, int bid, float* tile) {
  int b = bid >> 6, p0 = (bid & 63) << 6;
  int t = threadIdx.x;
  const float* xb = x + (size_t)b * 64 * 4096;
  f32x4 r[4];
#pragma unroll
  for (int i = 0; i < 4; ++i) {
    int idx = t + i * 256, c = idx >> 4, p4 = idx & 15;
    r[i] = *(const f32x4*)&xb[(size_t)c * 4096 + p0 + p4 * 4];
  }
#pragma unroll
  for (int i = 0; i < 4; ++i) {
    int idx = t + i * 256, c = idx >> 4, p4 = idx & 15;
#pragma unroll
    for (int j = 0; j < 4; ++j) tile[c * 65 + p4 * 4 + j] = r[i][j];
  }
  __syncthreads();
  int lane = t & 63, wvx = t >> 6;
  float gw = w[lane], gb = bias[lane];
#pragma unroll
  for (int pp = 0; pp < 16; pp += 2) {
    int p = wvx * 16 + pp;
    float v0 = tile[lane * 65 + p], v1 = tile[lane * 65 + p + 1];
    float s0 = v0, q0 = v0 * v0, s1 = v1, q1 = v1 * v1;
#pragma unroll
    for (int m = 1; m < 64; m <<= 1) {
      s0 += __shfl_xor(s0, m); q0 += __shfl_xor(q0, m);
      s1 += __shfl_xor(s1, m); q1 += __shfl_xor(q1, m);
    }
    float mu0 = s0 * (1.0f / 64.0f), var0 = q0 * (1.0f / 64.0f) - mu0 * mu0;
    float mu1 = s1 * (1.0f / 64.0f), var1 = q1 * (1.0f / 64.0f) - mu1 * mu1;
    tile[lane * 65 + p]     = (v0 - mu0) * rsqrtf(var0 + 1e-5f) * gw + gb;
    tile[lane * 65 + p + 1] = (v1 - mu1) * rsqrtf(var1 + 1e-5f) * gw + gb;
  }
  __syncthreads();
  u16* xfb = xf_pc + (size_t)b * 4096 * 64;
  u16* xtb = xfT + (size_t)b * 64 * 4096;
  int i0 = t >> 3, j8 = t & 7;
  float vc[2][8];
#pragma unroll
  for (int i = 0; i < 2; ++i)
#pragma unroll
    for (int j = 0; j < 8; ++j) vc[i][j] = tile[(j8 * 8 + j) * 65 + i0 + i * 32];
#pragma unroll
  for (int i = 0; i < 2; ++i) {
    u32x4 pk;
#pragma unroll
    for (int j = 0; j < 4; ++j)
      pk[j] = (u32)f2bf(vc[i][2 * j]) | ((u32)f2bf(vc[i][2 * j + 1]) << 16);
    *(u32x4*)&xfb[(size_t)(p0 + i0 + i * 32) * 64 + j8 * 8] = pk;
  }
  float vr[2][8];
#pragma unroll
  for (int i = 0; i < 2; ++i)
#pragma unroll
    for (int j = 0; j < 8; ++j) vr[i][j] = tile[(i0 + i * 32) * 65 + j8 * 8 + j];
#pragma unroll
  for (int i = 0; i < 2; ++i) {
    u32x4 pk;
#pragma unroll
    for (int j = 0; j < 4; ++j)
      pk[j] = (u32)f2bf(vr[i][2 * j]) | ((u32)f2bf(vr[i][2 * j + 1]) << 16);
    *(u32x4*)&xtb[(size_t)(i0 + i * 32) * 4096 + p0 + j8 * 8] = pk;
  }
}

// grid: Wq[0,2048) Wo[2048,4096) Wk[4096,4224) Wv[4224,4352) wperm[4352,4416) ln1[4416,5440)
__global__ __launch_bounds__(256) void prep_kernel(
    const float* __restrict__ W_q, u16* __restrict__ Wt_q,
    const float* __restrict__ W_o, u16* __restrict__ Wt_o,
    const float* __restrict__ W_k, u16* __restrict__ Wt_k,
    const float* __restrict__ W_v, u16* __restrict__ Wt_v,
    const float* __restrict__ W_rk, const float* __restrict__ W_rv,
    u16* __restrict__ Wt_rk, u16* __restrict__ Wt_rv,
    const float* __restrict__ x, const float* __restrict__ ln1w, const float* __restrict__ ln1b,
    u16* __restrict__ xf_pc, u16* __restrict__ xfT) {
  __shared__ float tile[128 * 65];
  int bid = blockIdx.x;
  if (bid < 2048)       wt_body2(W_q, Wt_q, 4096, 4096, bid, tile);
  else if (bid < 4096)  wt_body2(W_o, Wt_o, 4096, 4096, bid - 2048, tile);
  else if (bid < 4224)  wt_body2(W_k, Wt_k, 1024, 1024, bid - 4096, tile);
  else if (bid < 4352)  wt_body2(W_v, Wt_v, 1024, 1024, bid - 4224, tile);
  else if (bid < 4416)  wperm_body(W_rk, W_rv, Wt_rk, Wt_rv, bid - 4352);
  else                  ln1_body(x, ln1w, ln1b, xf_pc, xfT, bid - 4416, tile);
}

// ================= KV spatial reduction GEMM (64x64x256) + LN2 + transposed store =================
__global__ __launch_bounds__(256) void kv_kernel(const u16* __restrict__ xf_pc,
                                                 const u16* __restrict__ Wtk, const u16* __restrict__ Wtv,
                                                 const float* __restrict__ ln2w, const float* __restrict__ ln2b,
                                                 u16* __restrict__ kT, u16* __restrict__ vT) {
  __shared__ __align__(16) u16 As[64 * 264];
  __shared__ __align__(16) u16 Bk[64 * 264];
  __shared__ __align__(16) u16 Bv[64 * 264];
  u16* Tk = As;            // reuse As after compute (needs 64*72)
  u16* Tv = As + 64 * 72;  // 2*64*72 = 9216 <= 64*264
  int b = blockIdx.x >> 4, s0 = (blockIdx.x & 15) << 6;
  int t = threadIdx.x;
  const u16* Asrc = xf_pc + (size_t)b * 4096 * 64 + (size_t)s0 * 256;
#pragma unroll
  for (int i = 0; i < 8; ++i) {
    int id = t + i * 256, row = id >> 5, c16 = id & 31;
    *(u32x4*)&As[row * 264 + c16 * 8] = *(const u32x4*)&Asrc[(size_t)row * 256 + c16 * 8];
    *(u32x4*)&Bk[row * 264 + c16 * 8] = *(const u32x4*)&Wtk[(size_t)row * 256 + c16 * 8];
    *(u32x4*)&Bv[row * 264 + c16 * 8] = *(const u32x4*)&Wtv[(size_t)row * 256 + c16 * 8];
  }
  __syncthreads();
  int lane = t & 63, wv = t >> 6, lo = lane & 15, hi = lane >> 4;
  f32x4 acck[4] = {}, accv[4] = {};
  int arow = (wv * 16 + lo) * 264 + hi * 8;
#pragma unroll
  for (int kk = 0; kk < 8; ++kk) {
    bf16x8 a = *(const bf16x8*)&As[arow + kk * 32];
#pragma unroll
    for (int nf = 0; nf < 4; ++nf) {
      bf16x8 bk = *(const bf16x8*)&Bk[(nf * 16 + lo) * 264 + kk * 32 + hi * 8];
      bf16x8 bv = *(const bf16x8*)&Bv[(nf * 16 + lo) * 264 + kk * 32 + hi * 8];
      acck[nf] = MFMA16(a, bk, acck[nf]);
      accv[nf] = MFMA16(a, bv, accv[nf]);
    }
  }
  __syncthreads();  // done reading As; Tk/Tv alias it
  float w2[4], b2[4];
#pragma unroll
  for (int nf = 0; nf < 4; ++nf) { w2[nf] = ln2w[nf * 16 + lo]; b2[nf] = ln2b[nf * 16 + lo]; }
#pragma unroll
  for (int r = 0; r < 4; ++r) {
    float sk = 0.f, sk2 = 0.f, sv = 0.f, sv2 = 0.f;
#pragma unroll
    for (int nf = 0; nf < 4; ++nf) {
      float a = acck[nf][r], c = accv[nf][r];
      sk += a; sk2 += a * a; sv += c; sv2 += c * c;
    }
#pragma unroll
    for (int m = 1; m < 16; m <<= 1) {
      sk += __shfl_xor(sk, m); sk2 += __shfl_xor(sk2, m);
      sv += __shfl_xor(sv, m); sv2 += __shfl_xor(sv2, m);
    }
    float mk = sk * (1.f / 64.f), vk = sk2 * (1.f / 64.f) - mk * mk, rk = rsqrtf(vk + 1e-5f);
    float mv = sv * (1.f / 64.f), vv = sv2 * (1.f / 64.f) - mv * mv, rv = rsqrtf(vv + 1e-5f);
    int srow = wv * 16 + hi * 4 + r;
#pragma unroll
    for (int nf = 0; nf < 4; ++nf) {
      Tk[(nf * 16 + lo) * 72 + srow] = f2bf((acck[nf][r] - mk) * rk * w2[nf] + b2[nf]);
      Tv[(nf * 16 + lo) * 72 + srow] = f2bf((accv[nf][r] - mv) * rv * w2[nf] + b2[nf]);
    }
  }
  __syncthreads();
  u16* kdst = kT + (size_t)b * 64 * 1024 + s0;
  u16* vdst = vT + (size_t)b * 64 * 1024 + s0;
#pragma unroll
  for (int i = 0; i < 16; ++i) {
    int idx = t + i * 256, cp = idx >> 6, s = idx & 63;
    kdst[(size_t)cp * 1024 + s] = Tk[cp * 72 + s];
    vdst[(size_t)cp * 1024 + s] = Tv[cp * 72 + s];
  }
}

// ================= GEMM: BK=32, 3-buffer (48KB) counted-vmcnt pipeline, 4-slot XOR swizzle ==========
__device__ __forceinline__ void stage32(const u16* Ab, const u16* Bb, int K, int kt,
                                        u16* As, u16* Bs, int wv, int lane) {
#pragma unroll
  for (int i = 0; i < 2; ++i) {
    int cb = wv * 2 + i;            // uniform 1KB chunk-block
    int c = cb * 64 + lane;         // this lane's 16B chunk index
    int row = c >> 2, s = c & 3;
    int scol = (s ^ (row & 3)) << 3;
    gload16(Ab + (size_t)row * K + kt * 32 + scol, As + cb * 512);
    gload16(Bb + (size_t)row * K + kt * 32 + scol, Bs + cb * 512);
  }
}

__device__ __forceinline__ void compute32(const u16* As, const u16* Bs, f32x4 acc[4][4],
                                          int wm, int wn, int lo, int hi) {
  int slot = (hi ^ (lo & 3)) << 3;  // physical slot of logical k-chunk hi for rows ≡ lo (mod 4)
  bf16x8 a[4], bb[4];
#pragma unroll
  for (int i = 0; i < 4; ++i) {
    a[i]  = *(const bf16x8*)&As[(wm + i * 16 + lo) * 32 + slot];
    bb[i] = *(const bf16x8*)&Bs[(wn + i * 16 + lo) * 32 + slot];
  }
#pragma unroll
  for (int mi = 0; mi < 4; ++mi)
#pragma unroll
    for (int ni = 0; ni < 4; ++ni)
      acc[mi][ni] = MFMA16(a[mi], bb[ni], acc[mi][ni]);
}

// EPI 0: bf16 store C[m*N+n]
// EPI 1: bf16 store C[(n>>6)*chunkStride + m*64 + (n&63)]   (batch-split columns)
template <int EPI>
__device__ void gemm_body(const u16* __restrict__ A, const u16* __restrict__ Bm,
                          u16* __restrict__ Cc, int N, int K, int chunkStride,
                          int mt, int nt, int koff, int nk, u16* lds) {
  int t = threadIdx.x, lane = t & 63, wv = t >> 6;
  int wm = (wv >> 1) * 64, wn = (wv & 1) * 64;
  int lo = lane & 15, hi = lane >> 4;
  f32x4 acc[4][4] = {};
  const u16* Ab = A + (size_t)mt * 128 * K + koff;
  const u16* Bb = Bm + (size_t)nt * 128 * K + koff;
  u16* bufs[3] = {lds, lds + 8192, lds + 16384};  // 3 x 16KB = 48KB -> 3 blocks/CU
  stage32(Ab, Bb, K, 0, bufs[0], bufs[0] + 4096, wv, lane);
  stage32(Ab, Bb, K, 1, bufs[1], bufs[1] + 4096, wv, lane);
  for (int kt = 0; kt < nk; ++kt) {
    // counted wait BEFORE barrier: my stage-kt loads (4) retired, stage-kt+1's may fly
    if (kt + 1 < nk) asm volatile("s_waitcnt vmcnt(4)" ::: "memory");
    else             asm volatile("s_waitcnt vmcnt(0)" ::: "memory");
    __builtin_amdgcn_s_barrier();
    __builtin_amdgcn_sched_barrier(0);
    if (kt + 2 < nk) {
      u16* nb = bufs[(kt + 2) % 3];  // last read in compute(kt-1); all waves past barrier
      stage32(Ab, Bb, K, kt + 2, nb, nb + 4096, wv, lane);
    }
    u16* cb = bufs[kt % 3];
    compute32(cb, cb + 4096, acc, wm, wn, lo, hi);
  }
#pragma unroll
  for (int mi = 0; mi < 4; ++mi)
#pragma unroll
    for (int ni = 0; ni < 4; ++ni)
#pragma unroll
      for (int r = 0; r < 4; ++r) {
        int m = mt * 128 + wm + mi * 16 + hi * 4 + r;
        int n = nt * 128 + wn + ni * 16 + lo;
        float v = acc[mi][ni][r];
        if constexpr (EPI == 0) {
          Cc[(size_t)m * N + n] = f2bf(v);
        } else {
          Cc[(size_t)(n >> 6) * chunkStride + (size_t)m * 64 + (n & 63)] = f2bf(v);
        }
      }
}

// fused Q(split-K=4, 1024 blocks) + K(64) + V(64) projections
__global__ __launch_bounds__(256, 3) void qkv_kernel(
    const u16* __restrict__ Wt_q, const u16* __restrict__ xfT, u16* __restrict__ q_t,
    const u16* __restrict__ Wt_k, const u16* __restrict__ k_lnT, u16* __restrict__ kproj,
    const u16* __restrict__ v_lnT, const u16* __restrict__ Wt_v, u16* __restrict__ vproj) {
  __shared__ __align__(16) u16 lds[24576];
  int bid = blockIdx.x;
  if (bid < 1024) {
    // bijective XCD swizzle (nwg=1024): blocks sharing an A-panel land on one XCD
    int log = (bid & 7) * 128 + (bid >> 3);
    int kh = log >> 8, tile = log & 255, mt = tile >> 3, nt = tile & 7;
    gemm_body<1>(Wt_q, xfT, q_t + (size_t)kh * 4194304, 1024, 4096, 4096 * 64,
                 mt, nt, kh * 1024, 32, lds);
  } else if (bid < 1088) {
    int id = bid - 1024;
    gemm_body<1>(Wt_k, k_lnT, kproj, 1024, 1024, 1024 * 64, id >> 3, id & 7, 0, 32, lds);
  } else {
    int id = bid - 1088;
    gemm_body<0>(v_lnT, Wt_v, vproj, 1024, 1024, 0, id >> 3, id & 7, 0, 32, lds);
  }
}

// O-projection, split-K=2, 512 blocks, bf16 partials
__global__ __launch_bounds__(256, 3) void ogemm_kernel(const u16* __restrict__ o2,
                                                       const u16* __restrict__ Wt_o,
                                                       u16* __restrict__ o_part) {
  __shared__ __align__(16) u16 lds[24576];
  int bid = blockIdx.x;
  int log = (bid & 7) * 64 + (bid >> 3);
  int kh = log >> 8, tile = log & 255, mt = tile >> 5, nt = tile & 31;
  gemm_body<0>(o2, Wt_o, o_part + (size_t)kh * 4194304, 4096, 4096, 0,
               mt, nt, kh * 2048, 64, lds);
}

// out = x + p0 + p1   (f32 residual fused into split-K reduce)
__global__ __launch_bounds__(256) void oreduce_kernel(const float* __restrict__ x,
                                                      const u16* __restrict__ p0,
                                                      const u16* __restrict__ p1,
                                                      float* __restrict__ out) {
  size_t base = ((size_t)blockIdx.x * 256 + threadIdx.x) * 8;
  u32x4 a = *(const u32x4*)&p0[base];
  u32x4 b = *(const u32x4*)&p1[base];
  f32x4 x0 = *(const f32x4*)&x[base];
  f32x4 x1 = *(const f32x4*)&x[base + 4];
  float r[8];
#pragma unroll
  for (int j = 0; j < 4; ++j) {
    r[2 * j]     = __uint_as_float(a[j] << 16) + __uint_as_float(b[j] << 16);
    r[2 * j + 1] = __uint_as_float(a[j] & 0xFFFF0000u) + __uint_as_float(b[j] & 0xFFFF0000u);
  }
  f32x4 o0, o1;
#pragma unroll
  for (int j = 0; j < 4; ++j) { o0[j] = r[j] + x0[j]; o1[j] = r[4 + j] + x1[j]; }
  *(f32x4*)&out[base] = o0;
  *(f32x4*)&out[base + 4] = o1;
}

// ================= attention: per (b, head, 128-row q tile); full K (128) per block =================
__global__ __launch_bounds__(256) void attn_kernel(const u16* __restrict__ qp, const u16* __restrict__ kp,
                                                   const u16* __restrict__ vp, u16* __restrict__ o2) {
  __shared__ __align__(16) u16 Qs[128 * 72];
  __shared__ __align__(16) u16 Ks[128 * 72];
  __shared__ __align__(16) u16 Vs[64 * 136];
  __shared__ __align__(16) u16 Ps[128 * 136];
  int qt = blockIdx.x & 3, h = (blockIdx.x >> 2) & 7, b = blockIdx.x >> 5;
  int t = threadIdx.x, lane = t & 63, wv = t >> 6;
  int lo = lane & 15, hi = lane >> 4;
  const u16* qsrc = qp + (size_t)b * 262144 + (size_t)(h * 512 + qt * 128) * 64;
  const u16* ksrc = kp + (size_t)b * 1024 * 64 + (size_t)(h * 128) * 64;
  const u16* vsrc = vp + (size_t)b * 64 * 1024 + h * 128;
  // Q: sum 4 split-K bf16 partials, repack to bf16 (128 rows x 64 cols = 4 iters)
#pragma unroll
  for (int i = 0; i < 4; ++i) {
    int id = t + i * 256, row = id >> 3, c8 = id & 7;
    size_t goff = (size_t)row * 64 + c8 * 8;
    float f[8] = {0.f, 0.f, 0.f, 0.f, 0.f, 0.f, 0.f, 0.f};
#pragma unroll
    for (int kh = 0; kh < 4; ++kh) {
      u32x4 pk = *(const u32x4*)&qsrc[(size_t)kh * 4194304 + goff];
#pragma unroll
      for (int j = 0; j < 4; ++j) {
        f[2 * j]     += __uint_as_float(pk[j] << 16);
        f[2 * j + 1] += __uint_as_float(pk[j] & 0xFFFF0000u);
      }
    }
    u32x4 pko;
#pragma unroll
    for (int j = 0; j < 4; ++j) pko[j] = (u32)f2bf(f[2 * j]) | ((u32)f2bf(f[2 * j + 1]) << 16);
    *(u32x4*)&Qs[row * 72 + c8 * 8] = pko;
  }
#pragma unroll
  for (int i = 0; i < 4; ++i) {
    int id = t + i * 256;
    int row = id >> 3, c16 = id & 7;
    *(u32x4*)&Ks[row * 72 + c16 * 8] = *(const u32x4*)&ksrc[(size_t)row * 64 + c16 * 8];
    int vrow = id >> 4, v16 = id & 15;
    *(u32x4*)&Vs[vrow * 136 + v16 * 8] = *(const u32x4*)&vsrc[(size_t)vrow * 1024 + v16 * 8];
  }
  __syncthreads();
  // S = Q K^T : each wave owns 32 q-rows x 128 k-cols
  f32x4 s[2][8] = {};
#pragma unroll
  for (int kk = 0; kk < 2; ++kk) {
    bf16x8 a0 = *(const bf16x8*)&Qs[(wv * 32 + lo) * 72 + kk * 32 + hi * 8];
    bf16x8 a1 = *(const bf16x8*)&Qs[(wv * 32 + 16 + lo) * 72 + kk * 32 + hi * 8];
#pragma unroll
    for (int ni = 0; ni < 8; ++ni) {
      bf16x8 bb = *(const bf16x8*)&Ks[(ni * 16 + lo) * 72 + kk * 32 + hi * 8];
      s[0][ni] = MFMA16(a0, bb, s[0][ni]);
      s[1][ni] = MFMA16(a1, bb, s[1][ni]);
    }
  }
  const float inv_scale = 0.044194173824159216f;  // 1/sqrt(512)
#pragma unroll
  for (int mi = 0; mi < 2; ++mi)
#pragma unroll
    for (int ni = 0; ni < 8; ++ni) s[mi][ni] *= inv_scale;
#pragma unroll
  for (int mi = 0; mi < 2; ++mi) {
#pragma unroll
    for (int r = 0; r < 4; ++r) {
      float mx = -1e30f;
#pragma unroll
      for (int ni = 0; ni < 8; ++ni) mx = fmaxf(mx, s[mi][ni][r]);
#pragma unroll
      for (int m = 1; m < 16; m <<= 1) mx = fmaxf(mx, __shfl_xor(mx, m));
      float p[8], sum = 0.f;
#pragma unroll
      for (int ni = 0; ni < 8; ++ni) { p[ni] = __expf(s[mi][ni][r] - mx); sum += p[ni]; }
#pragma unroll
      for (int m = 1; m < 16; m <<= 1) sum += __shfl_xor(sum, m);
      float rs = 1.0f / sum;
      int row = wv * 32 + mi * 16 + hi * 4 + r;
#pragma unroll
      for (int ni = 0; ni < 8; ++ni) Ps[row * 136 + ni * 16 + lo] = f2bf(p[ni] * rs);
    }
  }
  __syncthreads();
  // O^T[c][lq] = sum_lk V[c][lk] * P[lq][lk] : each wave owns 64 c-rows x 32 lq-cols
  f32x4 o[4][2] = {};
#pragma unroll
  for (int kk = 0; kk < 4; ++kk) {
    bf16x8 b0 = *(const bf16x8*)&Ps[(wv * 32 + lo) * 136 + kk * 32 + hi * 8];
    bf16x8 b1 = *(const bf16x8*)&Ps[(wv * 32 + 16 + lo) * 136 + kk * 32 + hi * 8];
#pragma unroll
    for (int mi = 0; mi < 4; ++mi) {
      bf16x8 a = *(const bf16x8*)&Vs[(mi * 16 + lo) * 136 + kk * 32 + hi * 8];
      o[mi][0] = MFMA16(a, b0, o[mi][0]);
      o[mi][1] = MFMA16(a, b1, o[mi][1]);
    }
  }
  u16* od = o2 + (size_t)b * 64 * 4096 + h * 512 + qt * 128;
#pragma unroll
  for (int mi = 0; mi < 4; ++mi)
#pragma unroll
    for (int ni = 0; ni < 2; ++ni)
#pragma unroll
      for (int r = 0; r < 4; ++r) {
        int c = mi * 16 + hi * 4 + r;
        int lq = wv * 32 + ni * 16 + lo;
        od[(size_t)c * 4096 + lq] = f2bf(o[mi][ni][r]);
      }
}

extern "C" void kernel_launch(void* const* d_in, const int* in_sizes, int n_in,
                              void* d_out, int out_size, void* d_ws, size_t ws_size,
                              hipStream_t stream) {
  (void)in_sizes; (void)n_in; (void)out_size; (void)ws_size;
  const float* x    = (const float*)d_in[0];
  const float* ln1w = (const float*)d_in[1];
  const float* ln1b = (const float*)d_in[2];
  const float* ln2w = (const float*)d_in[3];
  const float* ln2b = (const float*)d_in[4];
  const float* W_rk = (const float*)d_in[5];
  const float* W_rv = (const float*)d_in[6];
  const float* W_q  = (const float*)d_in[7];
  const float* W_k  = (const float*)d_in[8];
  const float* W_v  = (const float*)d_in[9];
  const float* W_o  = (const float*)d_in[10];

  char* ws = (char*)d_ws;
  size_t off = 0;
  auto alloc = [&](size_t bytes) { char* p = ws + off; off += bytes; return p; };
  u16* Wt_q  = (u16*)alloc(4096ull * 4096 * 2);   // dead after qkv -> reused as o_part
  u16* Wt_o  = (u16*)alloc(4096ull * 4096 * 2);
  u16* Wt_k  = (u16*)alloc(1024ull * 1024 * 2);
  u16* Wt_v  = (u16*)alloc(1024ull * 1024 * 2);
  u16* Wt_rk = (u16*)alloc(64ull * 256 * 2);
  u16* Wt_rv = (u16*)alloc(64ull * 256 * 2);
  u16* xf_pc = (u16*)alloc(16ull * 4096 * 64 * 2);
  u16* xfT   = (u16*)alloc(16ull * 64 * 4096 * 2);  // dead after qkv -> reused as o2
  u16* k_lnT = (u16*)alloc(16ull * 64 * 1024 * 2);
  u16* v_lnT = (u16*)alloc(16ull * 64 * 1024 * 2);
  u16* q_t   = (u16*)alloc(4ull * 16 * 4096 * 64 * 2);  // 4 split-K partials
  u16* kproj = (u16*)alloc(16ull * 1024 * 64 * 2);
  u16* vproj = (u16*)alloc(16ull * 64 * 1024 * 2);
  u16* o2     = xfT;   // alias: xfT dead after qkv, o2 written by attn
  u16* o_part = Wt_q;  // alias: Wt_q dead after qkv, 2 partials (16.8 MB <= 33.5 MB)

  prep_kernel<<<5440, 256, 0, stream>>>(W_q, Wt_q, W_o, Wt_o, W_k, Wt_k, W_v, Wt_v,
                                        W_rk, W_rv, Wt_rk, Wt_rv, x, ln1w, ln1b, xf_pc, xfT);
  kv_kernel<<<256, 256, 0, stream>>>(xf_pc, Wt_rk, Wt_rv, ln2w, ln2b, k_lnT, v_lnT);
  // Q: q_t[kh][b][j][c] partials;  K: kproj[b][jk][c];  V: vproj[(b,c)][jv]
  qkv_kernel<<<1152, 256, 0, stream>>>(Wt_q, xfT, q_t, Wt_k, k_lnT, kproj, v_lnT, Wt_v, vproj);
  attn_kernel<<<512, 256, 0, stream>>>(q_t, kproj, vproj, o2);
  // O: o_part[kh][(b,c)][j2] = sum_j o2[(b,c)][j] * Wt_o[j2][j]
  ogemm_kernel<<<512, 256, 0, stream>>>(o2, Wt_o, o_part);
  oreduce_kernel<<<2048, 256, 0, stream>>>(x, o_part, o_part + 4194304, (float*)d_out);
}

// Round 9
// 210.849 us; speedup vs baseline: 1.1574x; 1.0034x over previous
//
#include <hip/hip_runtime.h>

typedef unsigned short u16;
typedef unsigned int u32;
typedef __attribute__((ext_vector_type(8))) __bf16 bf16x8;
typedef __attribute__((ext_vector_type(4))) float f32x4;
typedef __attribute__((ext_vector_type(4))) unsigned int u32x4;

#define MFMA16(a, b, c) __builtin_amdgcn_mfma_f32_16x16x32_bf16((a), (b), (c), 0, 0, 0)

__device__ __forceinline__ u16 f2bf(float f) {
  unsigned u = __float_as_uint(f);
  u += 0x7FFFu + ((u >> 16) & 1u);
  return (u16)(u >> 16);
}

typedef __attribute__((address_space(1))) const unsigned char gU8;
typedef __attribute__((address_space(3))) unsigned char sU8;
__device__ __forceinline__ void gload16(const void* g, void* l) {
  __builtin_amdgcn_global_load_lds((gU8*)g, (sU8*)l, 16, 0, 0);
}

// ================= building blocks: weight transpose (2-deep), wperm, LN1 =================
// wt_body2: one block transposes a 128k x 64n strip of W (f32, [K][N]) into Wt[n][k] bf16.
__device__ __forceinline__ void wt_body2(const float* __restrict__ W, u16* __restrict__ Wt,
                                         int K, int N, int bid, float* tile) {
  int ntn = N >> 6;
  int kt2 = bid / ntn, nt = bid % ntn;
  int t = threadIdx.x;
  const float* src = W + (size_t)kt2 * 128 * N + (size_t)nt * 64;
  f32x4 r[8];
#pragma unroll
  for (int i = 0; i < 8; ++i) {
    int idx = t + i * 256, row = idx >> 4, c4 = idx & 15;
    r[i] = *(const f32x4*)&src[(size_t)row * N + c4 * 4];
  }
#pragma unroll
  for (int i = 0; i < 8; ++i) {
    int idx = t + i * 256, row = idx >> 4, c4 = idx & 15;
#pragma unroll
    for (int j = 0; j < 4; ++j) tile[row * 65 + c4 * 4 + j] = r[i][j];
  }
  __syncthreads();
  u16* dst = Wt + (size_t)nt * 64 * K + (size_t)kt2 * 128;
  int g = t & 7, n0 = t >> 3;
#pragma unroll
  for (int i = 0; i < 2; ++i) {
    int n = n0 + i * 32;
    float v[16];
#pragma unroll
    for (int j = 0; j < 16; ++j) v[j] = tile[(g * 16 + j) * 65 + n];
    u32x4 pk0, pk1;
#pragma unroll
    for (int j = 0; j < 4; ++j) {
      pk0[j] = (u32)f2bf(v[2 * j]) | ((u32)f2bf(v[2 * j + 1]) << 16);
      pk1[j] = (u32)f2bf(v[8 + 2 * j]) | ((u32)f2bf(v[8 + 2 * j + 1]) << 16);
    }
    *(u32x4*)&dst[(size_t)n * K + g * 16] = pk0;
    *(u32x4*)&dst[(size_t)n * K + g * 16 + 8] = pk1;
  }
}

__device__ __forceinline__ void wperm_body(const float* __restrict__ Wrk, const float* __restrict__ Wrv,
                                           u16* __restrict__ Wtk, u16* __restrict__ Wtv, int bid) {
  int idx = bid * 256 + threadIdx.x;  // 16384 = 64 c' * 256 f
  int cp = idx >> 8, f = idx & 255;
  int k = ((f & 63) << 2) | (f >> 6);
  Wtk[idx] = f2bf(Wrk[k * 64 + cp]);
  Wtv[idx] = f2bf(Wrv[k * 64 + cp]);
}

__device__ __forceinline__ void ln1_body(const float* __restrict__ x, const float* __restrict__ w,
                                         const float* __restrict__ bias, u16* __restrict__ xf_pc,
                                         u16* __restrict__ xfT, int bid, float* tile) {
  int b = bid >> 6, p0 = (bid & 63) << 6;
  int t = threadIdx.x;
  const float* xb = x + (size_t)b * 64 * 4096;
  f32x4 r[4];
#pragma unroll
  for (int i = 0; i < 4; ++i) {
    int idx = t + i * 256, c = idx >> 4, p4 = idx & 15;
    r[i] = *(const f32x4*)&xb[(size_t)c * 4096 + p0 + p4 * 4];
  }
#pragma unroll
  for (int i = 0; i < 4; ++i) {
    int idx = t + i * 256, c = idx >> 4, p4 = idx & 15;
#pragma unroll
    for (int j = 0; j < 4; ++j) tile[c * 65 + p4 * 4 + j] = r[i][j];
  }
  __syncthreads();
  int lane = t & 63, wvx = t >> 6;
  float gw = w[lane], gb = bias[lane];
#pragma unroll
  for (int pp = 0; pp < 16; pp += 2) {
    int p = wvx * 16 + pp;
    float v0 = tile[lane * 65 + p], v1 = tile[lane * 65 + p + 1];
    float s0 = v0, q0 = v0 * v0, s1 = v1, q1 = v1 * v1;
#pragma unroll
    for (int m = 1; m < 64; m <<= 1) {
      s0 += __shfl_xor(s0, m); q0 += __shfl_xor(q0, m);
      s1 += __shfl_xor(s1, m); q1 += __shfl_xor(q1, m);
    }
    float mu0 = s0 * (1.0f / 64.0f), var0 = q0 * (1.0f / 64.0f) - mu0 * mu0;
    float mu1 = s1 * (1.0f / 64.0f), var1 = q1 * (1.0f / 64.0f) - mu1 * mu1;
    tile[lane * 65 + p]     = (v0 - mu0) * rsqrtf(var0 + 1e-5f) * gw + gb;
    tile[lane * 65 + p + 1] = (v1 - mu1) * rsqrtf(var1 + 1e-5f) * gw + gb;
  }
  __syncthreads();
  u16* xfb = xf_pc + (size_t)b * 4096 * 64;
  u16* xtb = xfT + (size_t)b * 64 * 4096;
  int i0 = t >> 3, j8 = t & 7;
  float vc[2][8];
#pragma unroll
  for (int i = 0; i < 2; ++i)
#pragma unroll
    for (int j = 0; j < 8; ++j) vc[i][j] = tile[(j8 * 8 + j) * 65 + i0 + i * 32];
#pragma unroll
  for (int i = 0; i < 2; ++i) {
    u32x4 pk;
#pragma unroll
    for (int j = 0; j < 4; ++j)
      pk[j] = (u32)f2bf(vc[i][2 * j]) | ((u32)f2bf(vc[i][2 * j + 1]) << 16);
    *(u32x4*)&xfb[(size_t)(p0 + i0 + i * 32) * 64 + j8 * 8] = pk;
  }
  float vr[2][8];
#pragma unroll
  for (int i = 0; i < 2; ++i)
#pragma unroll
    for (int j = 0; j < 8; ++j) vr[i][j] = tile[(i0 + i * 32) * 65 + j8 * 8 + j];
#pragma unroll
  for (int i = 0; i < 2; ++i) {
    u32x4 pk;
#pragma unroll
    for (int j = 0; j < 4; ++j)
      pk[j] = (u32)f2bf(vr[i][2 * j]) | ((u32)f2bf(vr[i][2 * j + 1]) << 16);
    *(u32x4*)&xtb[(size_t)(i0 + i * 32) * 4096 + p0 + j8 * 8] = pk;
  }
}

// ================= prep: Wq transpose + wperm + LN1 only (Wo/Wk/Wv migrated) =================
// grid: Wq[0,2048) wperm[2048,2112) ln1[2112,3136)
__global__ __launch_bounds__(256) void prep_kernel(
    const float* __restrict__ W_q, u16* __restrict__ Wt_q,
    const float* __restrict__ W_rk, const float* __restrict__ W_rv,
    u16* __restrict__ Wt_rk, u16* __restrict__ Wt_rv,
    const float* __restrict__ x, const float* __restrict__ ln1w, const float* __restrict__ ln1b,
    u16* __restrict__ xf_pc, u16* __restrict__ xfT) {
  __shared__ float tile[128 * 65];
  int bid = blockIdx.x;
  if (bid < 2048)       wt_body2(W_q, Wt_q, 4096, 4096, bid, tile);
  else if (bid < 2112)  wperm_body(W_rk, W_rv, Wt_rk, Wt_rv, bid - 2048);
  else                  ln1_body(x, ln1w, ln1b, xf_pc, xfT, bid - 2112, tile);
}

// ================= kv: KV-reduce GEMM + LN2 (256) ++ Wk/Wv transposes (128+128) =================
__global__ __launch_bounds__(256) void kv_kernel(const u16* __restrict__ xf_pc,
                                                 const u16* __restrict__ Wtk, const u16* __restrict__ Wtv,
                                                 const float* __restrict__ ln2w, const float* __restrict__ ln2b,
                                                 u16* __restrict__ kT, u16* __restrict__ vT,
                                                 const float* __restrict__ W_k, u16* __restrict__ Wt_k,
                                                 const float* __restrict__ W_v, u16* __restrict__ Wt_v) {
  __shared__ __align__(16) u16 As[64 * 264];   // 33792 B: also reused as f32 tile for wt blocks
  __shared__ __align__(16) u16 Bk[64 * 264];
  __shared__ __align__(16) u16 Bv[64 * 264];
  int bid0 = blockIdx.x;
  if (bid0 >= 256) {
    int id = bid0 - 256;
    if (id < 128) wt_body2(W_k, Wt_k, 1024, 1024, id, (float*)As);        // 33280 <= 33792
    else          wt_body2(W_v, Wt_v, 1024, 1024, id - 128, (float*)As);
    return;
  }
  u16* Tk = As;            // reuse As after compute (needs 64*72)
  u16* Tv = As + 64 * 72;
  int b = bid0 >> 4, s0 = (bid0 & 15) << 6;
  int t = threadIdx.x;
  const u16* Asrc = xf_pc + (size_t)b * 4096 * 64 + (size_t)s0 * 256;
#pragma unroll
  for (int i = 0; i < 8; ++i) {
    int id = t + i * 256, row = id >> 5, c16 = id & 31;
    *(u32x4*)&As[row * 264 + c16 * 8] = *(const u32x4*)&Asrc[(size_t)row * 256 + c16 * 8];
    *(u32x4*)&Bk[row * 264 + c16 * 8] = *(const u32x4*)&Wtk[(size_t)row * 256 + c16 * 8];
    *(u32x4*)&Bv[row * 264 + c16 * 8] = *(const u32x4*)&Wtv[(size_t)row * 256 + c16 * 8];
  }
  __syncthreads();
  int lane = t & 63, wv = t >> 6, lo = lane & 15, hi = lane >> 4;
  f32x4 acck[4] = {}, accv[4] = {};
  int arow = (wv * 16 + lo) * 264 + hi * 8;
#pragma unroll
  for (int kk = 0; kk < 8; ++kk) {
    bf16x8 a = *(const bf16x8*)&As[arow + kk * 32];
#pragma unroll
    for (int nf = 0; nf < 4; ++nf) {
      bf16x8 bk = *(const bf16x8*)&Bk[(nf * 16 + lo) * 264 + kk * 32 + hi * 8];
      bf16x8 bv = *(const bf16x8*)&Bv[(nf * 16 + lo) * 264 + kk * 32 + hi * 8];
      acck[nf] = MFMA16(a, bk, acck[nf]);
      accv[nf] = MFMA16(a, bv, accv[nf]);
    }
  }
  __syncthreads();  // done reading As; Tk/Tv alias it
  float w2[4], b2[4];
#pragma unroll
  for (int nf = 0; nf < 4; ++nf) { w2[nf] = ln2w[nf * 16 + lo]; b2[nf] = ln2b[nf * 16 + lo]; }
#pragma unroll
  for (int r = 0; r < 4; ++r) {
    float sk = 0.f, sk2 = 0.f, sv = 0.f, sv2 = 0.f;
#pragma unroll
    for (int nf = 0; nf < 4; ++nf) {
      float a = acck[nf][r], c = accv[nf][r];
      sk += a; sk2 += a * a; sv += c; sv2 += c * c;
    }
#pragma unroll
    for (int m = 1; m < 16; m <<= 1) {
      sk += __shfl_xor(sk, m); sk2 += __shfl_xor(sk2, m);
      sv += __shfl_xor(sv, m); sv2 += __shfl_xor(sv2, m);
    }
    float mk = sk * (1.f / 64.f), vk = sk2 * (1.f / 64.f) - mk * mk, rk = rsqrtf(vk + 1e-5f);
    float mv = sv * (1.f / 64.f), vv = sv2 * (1.f / 64.f) - mv * mv, rv = rsqrtf(vv + 1e-5f);
    int srow = wv * 16 + hi * 4 + r;
#pragma unroll
    for (int nf = 0; nf < 4; ++nf) {
      Tk[(nf * 16 + lo) * 72 + srow] = f2bf((acck[nf][r] - mk) * rk * w2[nf] + b2[nf]);
      Tv[(nf * 16 + lo) * 72 + srow] = f2bf((accv[nf][r] - mv) * rv * w2[nf] + b2[nf]);
    }
  }
  __syncthreads();
  u16* kdst = kT + (size_t)b * 64 * 1024 + s0;
  u16* vdst = vT + (size_t)b * 64 * 1024 + s0;
#pragma unroll
  for (int i = 0; i < 16; ++i) {
    int idx = t + i * 256, cp = idx >> 6, s = idx & 63;
    kdst[(size_t)cp * 1024 + s] = Tk[cp * 72 + s];
    vdst[(size_t)cp * 1024 + s] = Tv[cp * 72 + s];
  }
}

// ================= GEMM: BK=32, 3-buffer (48KB) counted-vmcnt pipeline, 4-slot XOR swizzle ==========
__device__ __forceinline__ void stage32(const u16* Ab, const u16* Bb, int K, int kt,
                                        u16* As, u16* Bs, int wv, int lane) {
#pragma unroll
  for (int i = 0; i < 2; ++i) {
    int cb = wv * 2 + i;            // uniform 1KB chunk-block
    int c = cb * 64 + lane;         // this lane's 16B chunk index
    int row = c >> 2, s = c & 3;
    int scol = (s ^ (row & 3)) << 3;
    gload16(Ab + (size_t)row * K + kt * 32 + scol, As + cb * 512);
    gload16(Bb + (size_t)row * K + kt * 32 + scol, Bs + cb * 512);
  }
}

__device__ __forceinline__ void compute32(const u16* As, const u16* Bs, f32x4 acc[4][4],
                                          int wm, int wn, int lo, int hi) {
  int slot = (hi ^ (lo & 3)) << 3;  // physical slot of logical k-chunk hi for rows ≡ lo (mod 4)
  bf16x8 a[4], bb[4];
#pragma unroll
  for (int i = 0; i < 4; ++i) {
    a[i]  = *(const bf16x8*)&As[(wm + i * 16 + lo) * 32 + slot];
    bb[i] = *(const bf16x8*)&Bs[(wn + i * 16 + lo) * 32 + slot];
  }
#pragma unroll
  for (int mi = 0; mi < 4; ++mi)
#pragma unroll
    for (int ni = 0; ni < 4; ++ni)
      acc[mi][ni] = MFMA16(a[mi], bb[ni], acc[mi][ni]);
}

// EPI 0: bf16 store C[m*N+n]
// EPI 1: bf16 store C[(n>>6)*chunkStride + m*64 + (n&63)]   (batch-split columns)
template <int EPI>
__device__ void gemm_body(const u16* __restrict__ A, const u16* __restrict__ Bm,
                          u16* __restrict__ Cc, int N, int K, int chunkStride,
                          int mt, int nt, int koff, int nk, u16* lds) {
  int t = threadIdx.x, lane = t & 63, wv = t >> 6;
  int wm = (wv >> 1) * 64, wn = (wv & 1) * 64;
  int lo = lane & 15, hi = lane >> 4;
  f32x4 acc[4][4] = {};
  const u16* Ab = A + (size_t)mt * 128 * K + koff;
  const u16* Bb = Bm + (size_t)nt * 128 * K + koff;
  u16* bufs[3] = {lds, lds + 8192, lds + 16384};  // 3 x 16KB = 48KB -> 3 blocks/CU
  stage32(Ab, Bb, K, 0, bufs[0], bufs[0] + 4096, wv, lane);
  stage32(Ab, Bb, K, 1, bufs[1], bufs[1] + 4096, wv, lane);
  for (int kt = 0; kt < nk; ++kt) {
    if (kt + 1 < nk) asm volatile("s_waitcnt vmcnt(4)" ::: "memory");
    else             asm volatile("s_waitcnt vmcnt(0)" ::: "memory");
    __builtin_amdgcn_s_barrier();
    __builtin_amdgcn_sched_barrier(0);
    if (kt + 2 < nk) {
      u16* nb = bufs[(kt + 2) % 3];
      stage32(Ab, Bb, K, kt + 2, nb, nb + 4096, wv, lane);
    }
    u16* cb = bufs[kt % 3];
    compute32(cb, cb + 4096, acc, wm, wn, lo, hi);
  }
#pragma unroll
  for (int mi = 0; mi < 4; ++mi)
#pragma unroll
    for (int ni = 0; ni < 4; ++ni)
#pragma unroll
      for (int r = 0; r < 4; ++r) {
        int m = mt * 128 + wm + mi * 16 + hi * 4 + r;
        int n = nt * 128 + wn + ni * 16 + lo;
        float v = acc[mi][ni][r];
        if constexpr (EPI == 0) {
          Cc[(size_t)m * N + n] = f2bf(v);
        } else {
          Cc[(size_t)(n >> 6) * chunkStride + (size_t)m * 64 + (n & 63)] = f2bf(v);
        }
      }
}

// fused Q(split-K=4, 1024) + K(64) + V(64) projections ++ Wo transpose (2048) riding spare BW
__global__ __launch_bounds__(256, 3) void qkv_kernel(
    const u16* __restrict__ Wt_q, const u16* __restrict__ xfT, u16* __restrict__ q_t,
    const u16* __restrict__ Wt_k, const u16* __restrict__ k_lnT, u16* __restrict__ kproj,
    const u16* __restrict__ v_lnT, const u16* __restrict__ Wt_v, u16* __restrict__ vproj,
    const float* __restrict__ W_o, u16* __restrict__ Wt_o) {
  __shared__ __align__(16) u16 lds[24576];  // 49152 B; wt_body2 needs 33280 B as float
  int bid = blockIdx.x;
  if (bid < 1024) {
    // bijective XCD swizzle (nwg=1024): blocks sharing an A-panel land on one XCD
    int log = (bid & 7) * 128 + (bid >> 3);
    int kh = log >> 8, tile = log & 255, mt = tile >> 3, nt = tile & 7;
    gemm_body<1>(Wt_q, xfT, q_t + (size_t)kh * 4194304, 1024, 4096, 4096 * 64,
                 mt, nt, kh * 1024, 32, lds);
  } else if (bid < 1088) {
    int id = bid - 1024;
    gemm_body<1>(Wt_k, k_lnT, kproj, 1024, 1024, 1024 * 64, id >> 3, id & 7, 0, 32, lds);
  } else if (bid < 1152) {
    int id = bid - 1088;
    gemm_body<0>(v_lnT, Wt_v, vproj, 1024, 1024, 0, id >> 3, id & 7, 0, 32, lds);
  } else {
    wt_body2(W_o, Wt_o, 4096, 4096, bid - 1152, (float*)lds);
  }
}

// O-projection, split-K=2, 512 blocks, bf16 partials
__global__ __launch_bounds__(256, 3) void ogemm_kernel(const u16* __restrict__ o2,
                                                       const u16* __restrict__ Wt_o,
                                                       u16* __restrict__ o_part) {
  __shared__ __align__(16) u16 lds[24576];
  int bid = blockIdx.x;
  int log = (bid & 7) * 64 + (bid >> 3);
  int kh = log >> 8, tile = log & 255, mt = tile >> 5, nt = tile & 31;
  gemm_body<0>(o2, Wt_o, o_part + (size_t)kh * 4194304, 4096, 4096, 0,
               mt, nt, kh * 2048, 64, lds);
}

// out = x + p0 + p1   (f32 residual fused into split-K reduce)
__global__ __launch_bounds__(256) void oreduce_kernel(const float* __restrict__ x,
                                                      const u16* __restrict__ p0,
                                                      const u16* __restrict__ p1,
                                                      float* __restrict__ out) {
  size_t base = ((size_t)blockIdx.x * 256 + threadIdx.x) * 8;
  u32x4 a = *(const u32x4*)&p0[base];
  u32x4 b = *(const u32x4*)&p1[base];
  f32x4 x0 = *(const f32x4*)&x[base];
  f32x4 x1 = *(const f32x4*)&x[base + 4];
  float r[8];
#pragma unroll
  for (int j = 0; j < 4; ++j) {
    r[2 * j]     = __uint_as_float(a[j] << 16) + __uint_as_float(b[j] << 16);
    r[2 * j + 1] = __uint_as_float(a[j] & 0xFFFF0000u) + __uint_as_float(b[j] & 0xFFFF0000u);
  }
  f32x4 o0, o1;
#pragma unroll
  for (int j = 0; j < 4; ++j) { o0[j] = r[j] + x0[j]; o1[j] = r[4 + j] + x1[j]; }
  *(f32x4*)&out[base] = o0;
  *(f32x4*)&out[base + 4] = o1;
}

// ================= attention: per (b, head, 128-row q tile); full K (128) per block =================
__global__ __launch_bounds__(256) void attn_kernel(const u16* __restrict__ qp, const u16* __restrict__ kp,
                                                   const u16* __restrict__ vp, u16* __restrict__ o2) {
  __shared__ __align__(16) u16 Qs[128 * 72];
  __shared__ __align__(16) u16 Ks[128 * 72];
  __shared__ __align__(16) u16 Vs[64 * 136];
  __shared__ __align__(16) u16 Ps[128 * 136];
  int qt = blockIdx.x & 3, h = (blockIdx.x >> 2) & 7, b = blockIdx.x >> 5;
  int t = threadIdx.x, lane = t & 63, wv = t >> 6;
  int lo = lane & 15, hi = lane >> 4;
  const u16* qsrc = qp + (size_t)b * 262144 + (size_t)(h * 512 + qt * 128) * 64;
  const u16* ksrc = kp + (size_t)b * 1024 * 64 + (size_t)(h * 128) * 64;
  const u16* vsrc = vp + (size_t)b * 64 * 1024 + h * 128;
  // Q: sum 4 split-K bf16 partials, repack to bf16 (128 rows x 64 cols = 4 iters)
#pragma unroll
  for (int i = 0; i < 4; ++i) {
    int id = t + i * 256, row = id >> 3, c8 = id & 7;
    size_t goff = (size_t)row * 64 + c8 * 8;
    float f[8] = {0.f, 0.f, 0.f, 0.f, 0.f, 0.f, 0.f, 0.f};
#pragma unroll
    for (int kh = 0; kh < 4; ++kh) {
      u32x4 pk = *(const u32x4*)&qsrc[(size_t)kh * 4194304 + goff];
#pragma unroll
      for (int j = 0; j < 4; ++j) {
        f[2 * j]     += __uint_as_float(pk[j] << 16);
        f[2 * j + 1] += __uint_as_float(pk[j] & 0xFFFF0000u);
      }
    }
    u32x4 pko;
#pragma unroll
    for (int j = 0; j < 4; ++j) pko[j] = (u32)f2bf(f[2 * j]) | ((u32)f2bf(f[2 * j + 1]) << 16);
    *(u32x4*)&Qs[row * 72 + c8 * 8] = pko;
  }
#pragma unroll
  for (int i = 0; i < 4; ++i) {
    int id = t + i * 256;
    int row = id >> 3, c16 = id & 7;
    *(u32x4*)&Ks[row * 72 + c16 * 8] = *(const u32x4*)&ksrc[(size_t)row * 64 + c16 * 8];
    int vrow = id >> 4, v16 = id & 15;
    *(u32x4*)&Vs[vrow * 136 + v16 * 8] = *(const u32x4*)&vsrc[(size_t)vrow * 1024 + v16 * 8];
  }
  __syncthreads();
  // S = Q K^T : each wave owns 32 q-rows x 128 k-cols
  f32x4 s[2][8] = {};
#pragma unroll
  for (int kk = 0; kk < 2; ++kk) {
    bf16x8 a0 = *(const bf16x8*)&Qs[(wv * 32 + lo) * 72 + kk * 32 + hi * 8];
    bf16x8 a1 = *(const bf16x8*)&Qs[(wv * 32 + 16 + lo) * 72 + kk * 32 + hi * 8];
#pragma unroll
    for (int ni = 0; ni < 8; ++ni) {
      bf16x8 bb = *(const bf16x8*)&Ks[(ni * 16 + lo) * 72 + kk * 32 + hi * 8];
      s[0][ni] = MFMA16(a0, bb, s[0][ni]);
      s[1][ni] = MFMA16(a1, bb, s[1][ni]);
    }
  }
  const float inv_scale = 0.044194173824159216f;  // 1/sqrt(512)
#pragma unroll
  for (int mi = 0; mi < 2; ++mi)
#pragma unroll
    for (int ni = 0; ni < 8; ++ni) s[mi][ni] *= inv_scale;
#pragma unroll
  for (int mi = 0; mi < 2; ++mi) {
#pragma unroll
    for (int r = 0; r < 4; ++r) {
      float mx = -1e30f;
#pragma unroll
      for (int ni = 0; ni < 8; ++ni) mx = fmaxf(mx, s[mi][ni][r]);
#pragma unroll
      for (int m = 1; m < 16; m <<= 1) mx = fmaxf(mx, __shfl_xor(mx, m));
      float p[8], sum = 0.f;
#pragma unroll
      for (int ni = 0; ni < 8; ++ni) { p[ni] = __expf(s[mi][ni][r] - mx); sum += p[ni]; }
#pragma unroll
      for (int m = 1; m < 16; m <<= 1) sum += __shfl_xor(sum, m);
      float rs = 1.0f / sum;
      int row = wv * 32 + mi * 16 + hi * 4 + r;
#pragma unroll
      for (int ni = 0; ni < 8; ++ni) Ps[row * 136 + ni * 16 + lo] = f2bf(p[ni] * rs);
    }
  }
  __syncthreads();
  // O^T[c][lq] = sum_lk V[c][lk] * P[lq][lk] : each wave owns 64 c-rows x 32 lq-cols
  f32x4 o[4][2] = {};
#pragma unroll
  for (int kk = 0; kk < 4; ++kk) {
    bf16x8 b0 = *(const bf16x8*)&Ps[(wv * 32 + lo) * 136 + kk * 32 + hi * 8];
    bf16x8 b1 = *(const bf16x8*)&Ps[(wv * 32 + 16 + lo) * 136 + kk * 32 + hi * 8];
#pragma unroll
    for (int mi = 0; mi < 4; ++mi) {
      bf16x8 a = *(const bf16x8*)&Vs[(mi * 16 + lo) * 136 + kk * 32 + hi * 8];
      o[mi][0] = MFMA16(a, b0, o[mi][0]);
      o[mi][1] = MFMA16(a, b1, o[mi][1]);
    }
  }
  u16* od = o2 + (size_t)b * 64 * 4096 + h * 512 + qt * 128;
#pragma unroll
  for (int mi = 0; mi < 4; ++mi)
#pragma unroll
    for (int ni = 0; ni < 2; ++ni)
#pragma unroll
      for (int r = 0; r < 4; ++r) {
        int c = mi * 16 + hi * 4 + r;
        int lq = wv * 32 + ni * 16 + lo;
        od[(size_t)c * 4096 + lq] = f2bf(o[mi][ni][r]);
      }
}

extern "C" void kernel_launch(void* const* d_in, const int* in_sizes, int n_in,
                              void* d_out, int out_size, void* d_ws, size_t ws_size,
                              hipStream_t stream) {
  (void)in_sizes; (void)n_in; (void)out_size; (void)ws_size;
  const float* x    = (const float*)d_in[0];
  const float* ln1w = (const float*)d_in[1];
  const float* ln1b = (const float*)d_in[2];
  const float* ln2w = (const float*)d_in[3];
  const float* ln2b = (const float*)d_in[4];
  const float* W_rk = (const float*)d_in[5];
  const float* W_rv = (const float*)d_in[6];
  const float* W_q  = (const float*)d_in[7];
  const float* W_k  = (const float*)d_in[8];
  const float* W_v  = (const float*)d_in[9];
  const float* W_o  = (const float*)d_in[10];

  char* ws = (char*)d_ws;
  size_t off = 0;
  auto alloc = [&](size_t bytes) { char* p = ws + off; off += bytes; return p; };
  u16* Wt_q  = (u16*)alloc(4096ull * 4096 * 2);   // dead after qkv -> reused as o_part
  u16* Wt_o  = (u16*)alloc(4096ull * 4096 * 2);
  u16* Wt_k  = (u16*)alloc(1024ull * 1024 * 2);
  u16* Wt_v  = (u16*)alloc(1024ull * 1024 * 2);
  u16* Wt_rk = (u16*)alloc(64ull * 256 * 2);
  u16* Wt_rv = (u16*)alloc(64ull * 256 * 2);
  u16* xf_pc = (u16*)alloc(16ull * 4096 * 64 * 2);
  u16* xfT   = (u16*)alloc(16ull * 64 * 4096 * 2);  // dead after qkv -> reused as o2
  u16* k_lnT = (u16*)alloc(16ull * 64 * 1024 * 2);
  u16* v_lnT = (u16*)alloc(16ull * 64 * 1024 * 2);
  u16* q_t   = (u16*)alloc(4ull * 16 * 4096 * 64 * 2);  // 4 split-K partials
  u16* kproj = (u16*)alloc(16ull * 1024 * 64 * 2);
  u16* vproj = (u16*)alloc(16ull * 64 * 1024 * 2);
  u16* o2     = xfT;   // alias: xfT dead after qkv, o2 written by attn
  u16* o_part = Wt_q;  // alias: Wt_q dead after qkv, 2 partials (16.8 MB <= 33.5 MB)

  prep_kernel<<<3136, 256, 0, stream>>>(W_q, Wt_q, W_rk, W_rv, Wt_rk, Wt_rv,
                                        x, ln1w, ln1b, xf_pc, xfT);
  kv_kernel<<<512, 256, 0, stream>>>(xf_pc, Wt_rk, Wt_rv, ln2w, ln2b, k_lnT, v_lnT,
                                     W_k, Wt_k, W_v, Wt_v);
  // Q: q_t[kh][b][j][c] partials;  K: kproj[b][jk][c];  V: vproj[(b,c)][jv];  + Wo transpose
  qkv_kernel<<<3200, 256, 0, stream>>>(Wt_q, xfT, q_t, Wt_k, k_lnT, kproj, v_lnT, Wt_v, vproj,
                                       W_o, Wt_o);
  attn_kernel<<<512, 256, 0, stream>>>(q_t, kproj, vproj, o2);
  // O: o_part[kh][(b,c)][j2] = sum_j o2[(b,c)][j] * Wt_o[j2][j]
  ogemm_kernel<<<512, 256, 0, stream>>>(o2, Wt_o, o_part);
  oreduce_kernel<<<2048, 256, 0, stream>>>(x, o_part, o_part + 4194304, (float*)d_out);
}